// Round 7
// baseline (430.832 us; speedup 1.0000x reference)
//
#include <hip/hip_runtime.h>
#include <hip/hip_bf16.h>
#include <math.h>

#define IN   128
#define HID  64
#define HEADS 4
#define NCLS 10

__device__ __forceinline__ float lrelu02(float x) { return fmaxf(x, 0.2f * x); }

// f32 -> bf16 bits with round-to-nearest-even
__device__ __forceinline__ unsigned short f2bf(float f) {
    unsigned u = __float_as_uint(f);
    u += 0x7FFFu + ((u >> 16) & 1u);
    return (unsigned short)(u >> 16);
}

template<int CTRL>
__device__ __forceinline__ float dppadd(float x) {
    int y = __builtin_amdgcn_update_dpp(0, __float_as_int(x), CTRL, 0xF, 0xF, true);
    return x + __int_as_float(y);
}
// sum over each 16-lane group (head): pure-VALU DPP tree
__device__ __forceinline__ float sum16(float p) {
    p = dppadd<0x128>(p);  // row_ror:8
    p = dppadd<0x124>(p);  // row_ror:4
    p = dppadd<0x4E>(p);   // quad_perm xor2
    p = dppadd<0xB1>(p);   // quad_perm xor1
    return p;
}

// ---------------- K1: h0 = x @ W_pre (blocks < rb) + dst histogram w/ rank capture (blocks >= rb) ----------------
__global__ __launch_bounds__(256) void k_pre_hist(const float* __restrict__ x,
                                                  const float* __restrict__ Wp,
                                                  float* __restrict__ h0, int n,
                                                  const int* __restrict__ dst, int* __restrict__ cnt,
                                                  int* __restrict__ rank, int E, int rb)
{
    __shared__ float sW[IN * HID];
    __shared__ float sx[64][IN + 4];
    int t = threadIdx.x;
    if ((int)blockIdx.x >= rb) {
        int e = ((int)blockIdx.x - rb) * 256 + t;
        if (e < E) rank[e] = atomicAdd(&cnt[dst[e]], 1);   // rank within dst segment
        return;
    }
    for (int i = 4 * t; i < IN * HID; i += 1024)
        *(float4*)&sW[i] = *(const float4*)&Wp[i];
    int row0 = blockIdx.x * 64;
    for (int i = t; i < 64 * (IN / 4); i += 256) {
        int r = i >> 5;
        int c4 = (i & 31) * 4;
        int row = row0 + r;
        float4 v = make_float4(0.f, 0.f, 0.f, 0.f);
        if (row < n) v = *(const float4*)&x[(size_t)row * IN + c4];
        *(float4*)&sx[r][c4] = v;
    }
    __syncthreads();
    int tc = t & 15, tr = t >> 4;
    int c0 = tc * 4, r0 = tr * 4;
    float acc[4][4] = {};
    #pragma unroll 4
    for (int k = 0; k < IN; k++) {
        float4 w = *(float4*)&sW[k * HID + c0];
        #pragma unroll
        for (int j = 0; j < 4; j++) {
            float xv = sx[r0 + j][k];
            acc[j][0] += xv * w.x; acc[j][1] += xv * w.y;
            acc[j][2] += xv * w.z; acc[j][3] += xv * w.w;
        }
    }
    #pragma unroll
    for (int j = 0; j < 4; j++) {
        int row = row0 + r0 + j;
        if (row < n)
            *(float4*)&h0[(size_t)row * HID + c0] =
                make_float4(acc[j][0], acc[j][1], acc[j][2], acc[j][3]);
    }
}

// ---------------- K2: xl/xr projections (+ bf16 mirror of xl) (blocks < rb) + scan stage1 (blocks >= rb) ----------------
__global__ __launch_bounds__(256) void k_lr_scan1(const float* __restrict__ h0,
                                                  const float* __restrict__ Wl, const float* __restrict__ bl,
                                                  const float* __restrict__ Wr, const float* __restrict__ br,
                                                  float* __restrict__ xl, float* __restrict__ xr,
                                                  unsigned short* __restrict__ xlh, int n,
                                                  const int* __restrict__ cnt, int* __restrict__ off,
                                                  int* __restrict__ bsum, int rb)
{
    __shared__ float smem[12672];
    int t = threadIdx.x;

    if ((int)blockIdx.x >= rb) {
        int* si = (int*)smem;
        int bid = (int)blockIdx.x - rb;
        int base = bid * 1024 + t * 4;
        int c0 = 0, c1 = 0, c2 = 0, c3 = 0;
        if (base + 3 < n) {
            int4 c = *(const int4*)&cnt[base];
            c0 = c.x; c1 = c.y; c2 = c.z; c3 = c.w;
        } else {
            if (base     < n) c0 = cnt[base];
            if (base + 1 < n) c1 = cnt[base + 1];
            if (base + 2 < n) c2 = cnt[base + 2];
            if (base + 3 < n) c3 = cnt[base + 3];
        }
        int lsum = c0 + c1 + c2 + c3;
        si[t] = lsum;
        __syncthreads();
        for (int d = 1; d < 256; d <<= 1) {
            int add = (t >= d) ? si[t - d] : 0;
            __syncthreads();
            si[t] += add;
            __syncthreads();
        }
        int excl = si[t] - lsum;
        if (base     < n) off[base]     = excl;
        if (base + 1 < n) off[base + 1] = excl + c0;
        if (base + 2 < n) off[base + 2] = excl + c0 + c1;
        if (base + 3 < n) off[base + 3] = excl + c0 + c1 + c2;
        if (t == 255) bsum[bid] = si[255];
        return;
    }

    float* sWl = smem;
    float* sWr = smem + 4096;
    float* sh  = smem + 8192;
    float* sbl = smem + 12544;
    float* sbr = smem + 12608;
    for (int i = 4 * t; i < HID * HID; i += 1024) {
        *(float4*)&sWl[i] = *(const float4*)&Wl[i];
        *(float4*)&sWr[i] = *(const float4*)&Wr[i];
    }
    if (t < HID) { sbl[t] = bl[t]; sbr[t] = br[t]; }
    int row0 = blockIdx.x * 64;
    for (int i = t; i < 64 * (HID / 4); i += 256) {
        int r = i >> 4, c4 = (i & 15) * 4;
        int row = row0 + r;
        float4 v = make_float4(0.f, 0.f, 0.f, 0.f);
        if (row < n) v = *(const float4*)&h0[(size_t)row * HID + c4];
        *(float4*)&sh[r * 68 + c4] = v;
    }
    __syncthreads();
    int tc = t & 15, tr = t >> 4;
    int c0 = tc * 4, r0 = tr * 4;
    float accl[4][4] = {}, accr[4][4] = {};
    #pragma unroll 4
    for (int k = 0; k < HID; k++) {
        float4 wl = *(float4*)&sWl[k * HID + c0];
        float4 wr = *(float4*)&sWr[k * HID + c0];
        #pragma unroll
        for (int j = 0; j < 4; j++) {
            float hv = sh[(r0 + j) * 68 + k];
            accl[j][0] += hv * wl.x; accl[j][1] += hv * wl.y;
            accl[j][2] += hv * wl.z; accl[j][3] += hv * wl.w;
            accr[j][0] += hv * wr.x; accr[j][1] += hv * wr.y;
            accr[j][2] += hv * wr.z; accr[j][3] += hv * wr.w;
        }
    }
    float4 b4l = *(float4*)&sbl[c0];
    float4 b4r = *(float4*)&sbr[c0];
    #pragma unroll
    for (int j = 0; j < 4; j++) {
        int row = row0 + r0 + j;
        if (row < n) {
            float l0 = accl[j][0] + b4l.x, l1 = accl[j][1] + b4l.y;
            float l2 = accl[j][2] + b4l.z, l3 = accl[j][3] + b4l.w;
            *(float4*)&xl[(size_t)row * HID + c0] = make_float4(l0, l1, l2, l3);
            ushort4 hb;
            hb.x = f2bf(l0); hb.y = f2bf(l1); hb.z = f2bf(l2); hb.w = f2bf(l3);
            *(ushort4*)&xlh[(size_t)row * HID + c0] = hb;
            *(float4*)&xr[(size_t)row * HID + c0] = make_float4(
                accr[j][0] + b4r.x, accr[j][1] + b4r.y, accr[j][2] + b4r.z, accr[j][3] + b4r.w);
        }
    }
}

// ---------------- Scan stage 2 ----------------
__global__ __launch_bounds__(1024) void k_scan2(const int* __restrict__ bsum, int* __restrict__ boff, int nb)
{
    __shared__ int s[1024];
    int i = threadIdx.x;
    int v = (i < nb) ? bsum[i] : 0;
    s[i] = v;
    __syncthreads();
    for (int d = 1; d < 1024; d <<= 1) {
        int add = (i >= d) ? s[i - d] : 0;
        __syncthreads();
        s[i] += add;
        __syncthreads();
    }
    if (i < nb) boff[i] = s[i] - v;
}

// ---------------- Scan stage 3: finalize off ----------------
__global__ __launch_bounds__(256) void k_scan3(int* __restrict__ off, const int* __restrict__ boff, int n)
{
    int i = blockIdx.x * 256 + threadIdx.x;
    if (i < n) off[i] += boff[i >> 10];
}

// ---------------- Scatter into CSR — atomic-free: pos = off[dst] + rank ----------------
__global__ __launch_bounds__(256) void k_scatter(const int* __restrict__ src, const int* __restrict__ dst,
                                                 const float* __restrict__ ew,
                                                 const int* __restrict__ off, const int* __restrict__ rank,
                                                 int2* __restrict__ csr, int E)
{
    int e4 = (blockIdx.x * 256 + threadIdx.x) * 4;
    if (e4 + 3 < E) {
        int4   s4 = *(const int4*)&src[e4];
        int4   d4 = *(const int4*)&dst[e4];
        int4   r4 = *(const int4*)&rank[e4];
        float4 w4 = *(const float4*)&ew[e4];
        int p0 = off[d4.x] + r4.x;
        int p1 = off[d4.y] + r4.y;
        int p2 = off[d4.z] + r4.z;
        int p3 = off[d4.w] + r4.w;
        csr[p0] = make_int2(s4.x, __float_as_int(w4.x));
        csr[p1] = make_int2(s4.y, __float_as_int(w4.y));
        csr[p2] = make_int2(s4.z, __float_as_int(w4.z));
        csr[p3] = make_int2(s4.w, __float_as_int(w4.w));
    } else {
        for (int e = e4; e < E; e++) {
            int p = off[dst[e]] + rank[e];
            csr[p] = make_int2(src[e], __float_as_int(ew[e]));
        }
    }
}

// ---------------- K_agg: one wave per dst; bf16 gathers; 8-deep pipeline; DPP reduction ----------------
__global__ __launch_bounds__(256) void k_agg(const int* __restrict__ off,
                                             const int2* __restrict__ csr,
                                             const unsigned short* __restrict__ xlh,
                                             const float* __restrict__ xl, const float* __restrict__ xr,
                                             const float* __restrict__ h0,
                                             const float* __restrict__ We, const float* __restrict__ att,
                                             const float* __restrict__ gb,
                                             float* __restrict__ hout, int n, int E)
{
    __shared__ float sWe[HID], sAtt[HID], sGb[HID];
    int t = threadIdx.x;
    if (t < HID) { sWe[t] = We[t]; sAtt[t] = att[t]; sGb[t] = gb[t]; }
    __syncthreads();
    int lane = t & 63;
    int v = blockIdx.x * 4 + (t >> 6);
    if (v >= n) return;

    int beg = off[v];
    int end = (v == n - 1) ? E : off[v + 1];

    float we = sWe[lane], at = sAtt[lane];
    float xrv = xr[(size_t)v * HID + lane];
    float xlv = xl[(size_t)v * HID + lane];

    float num = 0.f, den = 0.f, wsum = 0.f;

    for (int base = beg; base < end; base += 64) {
        int m = end - base; if (m > 64) m = 64;
        int sv = 0, wvb = 0;
        if (lane < m) {
            int2 cw = csr[base + lane];
            sv = cw.x;
            wvb = cw.y;
        }
        for (int j0 = 0; j0 < m; j0 += 8) {
            float xls[8], wj[8];
            // phase 1: scalar broadcasts + up to 8 independent bf16 gathers in flight
            #pragma unroll
            for (int u = 0; u < 8; u++) {
                if (j0 + u < m) {
                    int ss = __builtin_amdgcn_readlane(sv, j0 + u);
                    int wb = __builtin_amdgcn_readlane(wvb, j0 + u);
                    wj[u] = __int_as_float(wb);
                    const unsigned short* ph = xlh + ((unsigned)ss << 6);
                    xls[u] = __uint_as_float((unsigned)ph[lane] << 16);  // bf16 -> f32
                }
            }
            // phase 2: consume
            #pragma unroll
            for (int u = 0; u < 8; u++) {
                if (j0 + u < m) {
                    float ef = lrelu02(xls[u] + xrv + wj[u] * we);
                    float p = sum16(ef * at);
                    float ex = __expf(p);   // softmax shift-invariant; |alpha| << 1
                    num += ex * xls[u];
                    den += ex;
                    wsum += wj[u];
                }
            }
        }
    }

    float cntf = (float)(end - beg);
    float la = wsum / fmaxf(cntf, 1.0f);
    float ef = lrelu02(xlv + xrv + la * we);
    float p = sum16(ef * at);
    float exs = __expf(p);
    den += exs;
    num += exs * xlv;

    float o = num / den + sGb[lane];
    float h1 = o > 0.f ? o : expm1f(o);
    hout[(size_t)v * HID + lane] = h0[(size_t)v * HID + lane] + h1;
}

// ---------------- K_mlp: logits = relu(h@W1+b1)@W2+b2 ----------------
__global__ __launch_bounds__(256) void k_mlp(const float* __restrict__ h,
                                             const float* __restrict__ W1, const float* __restrict__ b1,
                                             const float* __restrict__ W2, const float* __restrict__ b2,
                                             float* __restrict__ logits, int n)
{
    __shared__ float sW1[HID * HID];
    __shared__ float sh[64][HID + 4];
    __shared__ float sz[64][HID + 4];
    __shared__ float sW2[HID * NCLS];
    __shared__ float sb1[HID], sb2[NCLS];
    int t = threadIdx.x;
    for (int i = 4 * t; i < HID * HID; i += 1024)
        *(float4*)&sW1[i] = *(const float4*)&W1[i];
    if (4 * t < HID * NCLS)
        *(float4*)&sW2[4 * t] = *(const float4*)&W2[4 * t];
    if (t < HID)  sb1[t] = b1[t];
    if (t < NCLS) sb2[t] = b2[t];
    int row0 = blockIdx.x * 64;
    for (int i = t; i < 64 * (HID / 4); i += 256) {
        int r = i >> 4, c4 = (i & 15) * 4;
        int row = row0 + r;
        float4 v = make_float4(0.f, 0.f, 0.f, 0.f);
        if (row < n) v = *(const float4*)&h[(size_t)row * HID + c4];
        *(float4*)&sh[r][c4] = v;
    }
    __syncthreads();
    int tc = t & 15, tr = t >> 4;
    int c0 = tc * 4, r0 = tr * 4;
    float4 b14 = *(float4*)&sb1[c0];
    float acc[4][4];
    #pragma unroll
    for (int j = 0; j < 4; j++) { acc[j][0] = b14.x; acc[j][1] = b14.y; acc[j][2] = b14.z; acc[j][3] = b14.w; }
    #pragma unroll 4
    for (int k = 0; k < HID; k++) {
        float4 w = *(float4*)&sW1[k * HID + c0];
        #pragma unroll
        for (int j = 0; j < 4; j++) {
            float hv = sh[r0 + j][k];
            acc[j][0] += hv * w.x; acc[j][1] += hv * w.y;
            acc[j][2] += hv * w.z; acc[j][3] += hv * w.w;
        }
    }
    #pragma unroll
    for (int j = 0; j < 4; j++) {
        sz[r0 + j][c0 + 0] = fmaxf(acc[j][0], 0.f);
        sz[r0 + j][c0 + 1] = fmaxf(acc[j][1], 0.f);
        sz[r0 + j][c0 + 2] = fmaxf(acc[j][2], 0.f);
        sz[r0 + j][c0 + 3] = fmaxf(acc[j][3], 0.f);
    }
    __syncthreads();
    for (int i = t; i < 64 * NCLS; i += 256) {
        int r = i / NCLS, c = i - r * NCLS;
        int row = row0 + r;
        float s = sb2[c];
        #pragma unroll 8
        for (int k = 0; k < HID; k++) s += sz[r][k] * sW2[k * NCLS + c];
        if (row < n) logits[(size_t)row * NCLS + c] = s;
    }
}

extern "C" void kernel_launch(void* const* d_in, const int* in_sizes, int n_in,
                              void* d_out, int out_size, void* d_ws, size_t ws_size,
                              hipStream_t stream)
{
    const float* x   = (const float*)d_in[0];
    const float* ew  = (const float*)d_in[1];
    const float* Wp  = (const float*)d_in[2];
    const float* Wl  = (const float*)d_in[3];
    const float* bl  = (const float*)d_in[4];
    const float* Wr  = (const float*)d_in[5];
    const float* br  = (const float*)d_in[6];
    const float* att = (const float*)d_in[7];
    const float* We  = (const float*)d_in[8];
    const float* gb  = (const float*)d_in[9];
    const float* W1  = (const float*)d_in[10];
    const float* b1  = (const float*)d_in[11];
    const float* W2  = (const float*)d_in[12];
    const float* b2  = (const float*)d_in[13];
    const int*   ei  = (const int*)d_in[14];

    int n = in_sizes[0] / IN;
    int E = in_sizes[1];
    const int* src = ei;
    const int* dst = ei + E;

    float* h0    = (float*)d_ws;
    float* xl    = h0 + (size_t)n * HID;
    float* xr    = xl + (size_t)n * HID;
    int*   cnt   = (int*)(xr + (size_t)n * HID);   // zeroed
    int*   off   = cnt + n;
    int*   bsum  = off + n;
    int*   boff  = bsum + 1024;
    int*   rank  = boff + 1024;
    int2*  csr   = (int2*)(rank + ((E + 1) & ~1));
    unsigned short* xlh = (unsigned short*)(csr + E);

    float* hout   = (float*)d_out;
    float* logits = hout + (size_t)n * HID;

    hipMemsetAsync(cnt, 0, (size_t)n * sizeof(int), stream);

    int rb = (n + 63) / 64;
    int nb = (n + 1023) / 1024;
    int Eb = (E + 255) / 256;

    k_pre_hist<<<rb + Eb, 256, 0, stream>>>(x, Wp, h0, n, dst, cnt, rank, E, rb);
    k_lr_scan1<<<rb + nb, 256, 0, stream>>>(h0, Wl, bl, Wr, br, xl, xr, xlh, n, cnt, off, bsum, rb);
    k_scan2<<<1, 1024, 0, stream>>>(bsum, boff, nb);
    k_scan3<<<(n + 255) / 256, 256, 0, stream>>>(off, boff, n);
    k_scatter<<<(E / 4 + 255) / 256, 256, 0, stream>>>(src, dst, ew, off, rank, csr, E);
    k_agg <<<(n + 3) / 4, 256, 0, stream>>>(off, csr, xlh, xl, xr, h0, We, att, gb, hout, n, E);
    k_mlp <<<rb, 256, 0, stream>>>(hout, W1, b1, W2, b2, logits, n);
}

// Round 8
// 379.924 us; speedup vs baseline: 1.1340x; 1.1340x over previous
//
#include <hip/hip_runtime.h>
#include <hip/hip_bf16.h>
#include <math.h>

#define IN   128
#define HID  64
#define HEADS 4
#define NCLS 10

__device__ __forceinline__ float lrelu02(float x) { return fmaxf(x, 0.2f * x); }

// f32 -> bf16 bits with round-to-nearest-even
__device__ __forceinline__ unsigned short f2bf(float f) {
    unsigned u = __float_as_uint(f);
    u += 0x7FFFu + ((u >> 16) & 1u);
    return (unsigned short)(u >> 16);
}
__device__ __forceinline__ float bf2f(unsigned short h) {
    return __uint_as_float((unsigned)h << 16);
}

template<int CTRL>
__device__ __forceinline__ float dppadd(float x) {
    int y = __builtin_amdgcn_update_dpp(0, __float_as_int(x), CTRL, 0xF, 0xF, true);
    return x + __int_as_float(y);
}
// sum over each 16-lane group (head): pure-VALU DPP tree
__device__ __forceinline__ float sum16(float p) {
    p = dppadd<0x128>(p);  // row_ror:8
    p = dppadd<0x124>(p);  // row_ror:4
    p = dppadd<0x4E>(p);   // quad_perm xor2
    p = dppadd<0xB1>(p);   // quad_perm xor1
    return p;
}

// ---------------- K1: h0 = x @ W_pre (blocks < rb) + dst histogram w/ rank capture (blocks >= rb) ----------------
__global__ __launch_bounds__(256) void k_pre_hist(const float* __restrict__ x,
                                                  const float* __restrict__ Wp,
                                                  float* __restrict__ h0, int n,
                                                  const int* __restrict__ dst, int* __restrict__ cnt,
                                                  int* __restrict__ rank, int E, int rb)
{
    __shared__ float sW[IN * HID];
    __shared__ float sx[64][IN + 4];
    int t = threadIdx.x;
    if ((int)blockIdx.x >= rb) {
        int e4 = (((int)blockIdx.x - rb) * 256 + t) * 4;
        if (e4 + 3 < E) {
            int4 d4 = *(const int4*)&dst[e4];
            int4 r4;
            r4.x = atomicAdd(&cnt[d4.x], 1);
            r4.y = atomicAdd(&cnt[d4.y], 1);
            r4.z = atomicAdd(&cnt[d4.z], 1);
            r4.w = atomicAdd(&cnt[d4.w], 1);
            *(int4*)&rank[e4] = r4;
        } else {
            for (int e = e4; e < E; e++) rank[e] = atomicAdd(&cnt[dst[e]], 1);
        }
        return;
    }
    for (int i = 4 * t; i < IN * HID; i += 1024)
        *(float4*)&sW[i] = *(const float4*)&Wp[i];
    int row0 = blockIdx.x * 64;
    for (int i = t; i < 64 * (IN / 4); i += 256) {
        int r = i >> 5;
        int c4 = (i & 31) * 4;
        int row = row0 + r;
        float4 v = make_float4(0.f, 0.f, 0.f, 0.f);
        if (row < n) v = *(const float4*)&x[(size_t)row * IN + c4];
        *(float4*)&sx[r][c4] = v;
    }
    __syncthreads();
    int tc = t & 15, tr = t >> 4;
    int c0 = tc * 4, r0 = tr * 4;
    float acc[4][4] = {};
    #pragma unroll 4
    for (int k = 0; k < IN; k++) {
        float4 w = *(float4*)&sW[k * HID + c0];
        #pragma unroll
        for (int j = 0; j < 4; j++) {
            float xv = sx[r0 + j][k];
            acc[j][0] += xv * w.x; acc[j][1] += xv * w.y;
            acc[j][2] += xv * w.z; acc[j][3] += xv * w.w;
        }
    }
    #pragma unroll
    for (int j = 0; j < 4; j++) {
        int row = row0 + r0 + j;
        if (row < n)
            *(float4*)&h0[(size_t)row * HID + c0] =
                make_float4(acc[j][0], acc[j][1], acc[j][2], acc[j][3]);
    }
}

// ---------------- K2: xl(bf16)/xr projections (blocks < rb) + scan stage1 (blocks >= rb) ----------------
__global__ __launch_bounds__(256) void k_lr_scan1(const float* __restrict__ h0,
                                                  const float* __restrict__ Wl, const float* __restrict__ bl,
                                                  const float* __restrict__ Wr, const float* __restrict__ br,
                                                  float* __restrict__ xr,
                                                  unsigned short* __restrict__ xlh, int n,
                                                  const int* __restrict__ cnt, int* __restrict__ off,
                                                  int* __restrict__ bsum, int rb)
{
    __shared__ float smem[12672];
    int t = threadIdx.x;

    if ((int)blockIdx.x >= rb) {
        int* si = (int*)smem;
        int bid = (int)blockIdx.x - rb;
        int base = bid * 1024 + t * 4;
        int c0 = 0, c1 = 0, c2 = 0, c3 = 0;
        if (base + 3 < n) {
            int4 c = *(const int4*)&cnt[base];
            c0 = c.x; c1 = c.y; c2 = c.z; c3 = c.w;
        } else {
            if (base     < n) c0 = cnt[base];
            if (base + 1 < n) c1 = cnt[base + 1];
            if (base + 2 < n) c2 = cnt[base + 2];
            if (base + 3 < n) c3 = cnt[base + 3];
        }
        int lsum = c0 + c1 + c2 + c3;
        si[t] = lsum;
        __syncthreads();
        for (int d = 1; d < 256; d <<= 1) {
            int add = (t >= d) ? si[t - d] : 0;
            __syncthreads();
            si[t] += add;
            __syncthreads();
        }
        int excl = si[t] - lsum;
        if (base     < n) off[base]     = excl;
        if (base + 1 < n) off[base + 1] = excl + c0;
        if (base + 2 < n) off[base + 2] = excl + c0 + c1;
        if (base + 3 < n) off[base + 3] = excl + c0 + c1 + c2;
        if (t == 255) bsum[bid] = si[255];
        return;
    }

    float* sWl = smem;
    float* sWr = smem + 4096;
    float* sh  = smem + 8192;
    float* sbl = smem + 12544;
    float* sbr = smem + 12608;
    for (int i = 4 * t; i < HID * HID; i += 1024) {
        *(float4*)&sWl[i] = *(const float4*)&Wl[i];
        *(float4*)&sWr[i] = *(const float4*)&Wr[i];
    }
    if (t < HID) { sbl[t] = bl[t]; sbr[t] = br[t]; }
    int row0 = blockIdx.x * 64;
    for (int i = t; i < 64 * (HID / 4); i += 256) {
        int r = i >> 4, c4 = (i & 15) * 4;
        int row = row0 + r;
        float4 v = make_float4(0.f, 0.f, 0.f, 0.f);
        if (row < n) v = *(const float4*)&h0[(size_t)row * HID + c4];
        *(float4*)&sh[r * 68 + c4] = v;
    }
    __syncthreads();
    int tc = t & 15, tr = t >> 4;
    int c0 = tc * 4, r0 = tr * 4;
    float accl[4][4] = {}, accr[4][4] = {};
    #pragma unroll 4
    for (int k = 0; k < HID; k++) {
        float4 wl = *(float4*)&sWl[k * HID + c0];
        float4 wr = *(float4*)&sWr[k * HID + c0];
        #pragma unroll
        for (int j = 0; j < 4; j++) {
            float hv = sh[(r0 + j) * 68 + k];
            accl[j][0] += hv * wl.x; accl[j][1] += hv * wl.y;
            accl[j][2] += hv * wl.z; accl[j][3] += hv * wl.w;
            accr[j][0] += hv * wr.x; accr[j][1] += hv * wr.y;
            accr[j][2] += hv * wr.z; accr[j][3] += hv * wr.w;
        }
    }
    float4 b4l = *(float4*)&sbl[c0];
    float4 b4r = *(float4*)&sbr[c0];
    #pragma unroll
    for (int j = 0; j < 4; j++) {
        int row = row0 + r0 + j;
        if (row < n) {
            ushort4 hb;
            hb.x = f2bf(accl[j][0] + b4l.x);
            hb.y = f2bf(accl[j][1] + b4l.y);
            hb.z = f2bf(accl[j][2] + b4l.z);
            hb.w = f2bf(accl[j][3] + b4l.w);
            *(ushort4*)&xlh[(size_t)row * HID + c0] = hb;
            *(float4*)&xr[(size_t)row * HID + c0] = make_float4(
                accr[j][0] + b4r.x, accr[j][1] + b4r.y, accr[j][2] + b4r.z, accr[j][3] + b4r.w);
        }
    }
}

// ---------------- Scan stage 2 ----------------
__global__ __launch_bounds__(1024) void k_scan2(const int* __restrict__ bsum, int* __restrict__ boff, int nb)
{
    __shared__ int s[1024];
    int i = threadIdx.x;
    int v = (i < nb) ? bsum[i] : 0;
    s[i] = v;
    __syncthreads();
    for (int d = 1; d < 1024; d <<= 1) {
        int add = (i >= d) ? s[i - d] : 0;
        __syncthreads();
        s[i] += add;
        __syncthreads();
    }
    if (i < nb) boff[i] = s[i] - v;
}

// ---------------- Scatter into CSR — atomic-free: pos = off[dst] + boff[dst>>10] + rank ----------------
__global__ __launch_bounds__(256) void k_scatter(const int* __restrict__ src, const int* __restrict__ dst,
                                                 const float* __restrict__ ew,
                                                 const int* __restrict__ off, const int* __restrict__ boff,
                                                 const int* __restrict__ rank,
                                                 int2* __restrict__ csr, int E)
{
    int e4 = (blockIdx.x * 256 + threadIdx.x) * 4;
    if (e4 + 3 < E) {
        int4   s4 = *(const int4*)&src[e4];
        int4   d4 = *(const int4*)&dst[e4];
        int4   r4 = *(const int4*)&rank[e4];
        float4 w4 = *(const float4*)&ew[e4];
        int p0 = off[d4.x] + boff[d4.x >> 10] + r4.x;
        int p1 = off[d4.y] + boff[d4.y >> 10] + r4.y;
        int p2 = off[d4.z] + boff[d4.z >> 10] + r4.z;
        int p3 = off[d4.w] + boff[d4.w >> 10] + r4.w;
        csr[p0] = make_int2(s4.x, __float_as_int(w4.x));
        csr[p1] = make_int2(s4.y, __float_as_int(w4.y));
        csr[p2] = make_int2(s4.z, __float_as_int(w4.z));
        csr[p3] = make_int2(s4.w, __float_as_int(w4.w));
    } else {
        for (int e = e4; e < E; e++) {
            int p = off[dst[e]] + boff[dst[e] >> 10] + rank[e];
            csr[p] = make_int2(src[e], __float_as_int(ew[e]));
        }
    }
}

// ---------------- K_agg: one wave per dst; bf16 gathers; unguarded 8-deep pipeline; DPP + exp2 ----------------
__global__ __launch_bounds__(256) void k_agg(const int* __restrict__ off, const int* __restrict__ boff,
                                             const int2* __restrict__ csr,
                                             const unsigned short* __restrict__ xlh,
                                             const float* __restrict__ xr,
                                             const float* __restrict__ h0,
                                             const float* __restrict__ We, const float* __restrict__ att,
                                             const float* __restrict__ gb,
                                             float* __restrict__ hout, int n, int E)
{
    __shared__ float sWe[HID], sAtt[HID], sGb[HID];
    int t = threadIdx.x;
    if (t < HID) {
        sWe[t] = We[t];
        sAtt[t] = att[t] * 1.44269504f;   // pre-scale by log2(e): e^p == exp2(p*log2e)
        sGb[t] = gb[t];
    }
    __syncthreads();
    int lane = t & 63;
    int v = blockIdx.x * 4 + (t >> 6);
    if (v >= n) return;

    int beg = off[v] + boff[v >> 10];
    int end = (v == n - 1) ? E : off[v + 1] + boff[(v + 1) >> 10];

    float we = sWe[lane], at = sAtt[lane];
    float xrv = xr[(size_t)v * HID + lane];
    float xlv = bf2f(xlh[((size_t)v << 6) + lane]);

    float num = 0.f, den = 0.f, wsum = 0.f;

    for (int base = beg; base < end; base += 64) {
        int m = end - base; if (m > 64) m = 64;
        int sv = 0, wvb = 0;
        if (lane < m) {
            int2 cw = csr[base + lane];
            sv = cw.x;
            wvb = cw.y;
        }
        int m8 = m & ~7;
        int j0 = 0;
        for (; j0 < m8; j0 += 8) {
            float xls[8], wj[8];
            // phase 1: scalar broadcasts + 8 independent bf16 gathers in flight (no guards)
            #pragma unroll
            for (int u = 0; u < 8; u++) {
                int ss = __builtin_amdgcn_readlane(sv, j0 + u);
                int wb = __builtin_amdgcn_readlane(wvb, j0 + u);
                wj[u] = __int_as_float(wb);
                const unsigned short* ph = xlh + ((unsigned)ss << 6);
                xls[u] = bf2f(ph[lane]);
            }
            // phase 2: consume (no guards)
            #pragma unroll
            for (int u = 0; u < 8; u++) {
                float ef = lrelu02(xls[u] + xrv + wj[u] * we);
                float p = sum16(ef * at);
                float ex = __builtin_amdgcn_exp2f(p);
                num += ex * xls[u];
                den += ex;
                wsum += wj[u];
            }
        }
        for (; j0 < m; j0++) {
            int ss = __builtin_amdgcn_readlane(sv, j0);
            int wb = __builtin_amdgcn_readlane(wvb, j0);
            float w = __int_as_float(wb);
            float xls = bf2f(xlh[((unsigned)ss << 6) + lane]);
            float ef = lrelu02(xls + xrv + w * we);
            float p = sum16(ef * at);
            float ex = __builtin_amdgcn_exp2f(p);
            num += ex * xls;
            den += ex;
            wsum += w;
        }
    }

    // analytic self-loop
    float cntf = (float)(end - beg);
    float la = wsum / fmaxf(cntf, 1.0f);
    float ef = lrelu02(xlv + xrv + la * we);
    float p = sum16(ef * at);
    float exs = __builtin_amdgcn_exp2f(p);
    den += exs;
    num += exs * xlv;

    float o = num / den + sGb[lane];
    float h1 = o > 0.f ? o : expm1f(o);
    hout[(size_t)v * HID + lane] = h0[(size_t)v * HID + lane] + h1;
}

// ---------------- K_mlp: logits = relu(h@W1+b1)@W2+b2 ----------------
__global__ __launch_bounds__(256) void k_mlp(const float* __restrict__ h,
                                             const float* __restrict__ W1, const float* __restrict__ b1,
                                             const float* __restrict__ W2, const float* __restrict__ b2,
                                             float* __restrict__ logits, int n)
{
    __shared__ float sW1[HID * HID];
    __shared__ float sh[64][HID + 4];
    __shared__ float sz[64][HID + 4];
    __shared__ float sW2[HID * NCLS];
    __shared__ float sb1[HID], sb2[NCLS];
    int t = threadIdx.x;
    for (int i = 4 * t; i < HID * HID; i += 1024)
        *(float4*)&sW1[i] = *(const float4*)&W1[i];
    if (4 * t < HID * NCLS)
        *(float4*)&sW2[4 * t] = *(const float4*)&W2[4 * t];
    if (t < HID)  sb1[t] = b1[t];
    if (t < NCLS) sb2[t] = b2[t];
    int row0 = blockIdx.x * 64;
    for (int i = t; i < 64 * (HID / 4); i += 256) {
        int r = i >> 4, c4 = (i & 15) * 4;
        int row = row0 + r;
        float4 v = make_float4(0.f, 0.f, 0.f, 0.f);
        if (row < n) v = *(const float4*)&h[(size_t)row * HID + c4];
        *(float4*)&sh[r][c4] = v;
    }
    __syncthreads();
    int tc = t & 15, tr = t >> 4;
    int c0 = tc * 4, r0 = tr * 4;
    float4 b14 = *(float4*)&sb1[c0];
    float acc[4][4];
    #pragma unroll
    for (int j = 0; j < 4; j++) { acc[j][0] = b14.x; acc[j][1] = b14.y; acc[j][2] = b14.z; acc[j][3] = b14.w; }
    #pragma unroll 4
    for (int k = 0; k < HID; k++) {
        float4 w = *(float4*)&sW1[k * HID + c0];
        #pragma unroll
        for (int j = 0; j < 4; j++) {
            float hv = sh[r0 + j][k];
            acc[j][0] += hv * w.x; acc[j][1] += hv * w.y;
            acc[j][2] += hv * w.z; acc[j][3] += hv * w.w;
        }
    }
    #pragma unroll
    for (int j = 0; j < 4; j++) {
        sz[r0 + j][c0 + 0] = fmaxf(acc[j][0], 0.f);
        sz[r0 + j][c0 + 1] = fmaxf(acc[j][1], 0.f);
        sz[r0 + j][c0 + 2] = fmaxf(acc[j][2], 0.f);
        sz[r0 + j][c0 + 3] = fmaxf(acc[j][3], 0.f);
    }
    __syncthreads();
    for (int i = t; i < 64 * NCLS; i += 256) {
        int r = i / NCLS, c = i - r * NCLS;
        int row = row0 + r;
        float s = sb2[c];
        #pragma unroll 8
        for (int k = 0; k < HID; k++) s += sz[r][k] * sW2[k * NCLS + c];
        if (row < n) logits[(size_t)row * NCLS + c] = s;
    }
}

extern "C" void kernel_launch(void* const* d_in, const int* in_sizes, int n_in,
                              void* d_out, int out_size, void* d_ws, size_t ws_size,
                              hipStream_t stream)
{
    const float* x   = (const float*)d_in[0];
    const float* ew  = (const float*)d_in[1];
    const float* Wp  = (const float*)d_in[2];
    const float* Wl  = (const float*)d_in[3];
    const float* bl  = (const float*)d_in[4];
    const float* Wr  = (const float*)d_in[5];
    const float* br  = (const float*)d_in[6];
    const float* att = (const float*)d_in[7];
    const float* We  = (const float*)d_in[8];
    const float* gb  = (const float*)d_in[9];
    const float* W1  = (const float*)d_in[10];
    const float* b1  = (const float*)d_in[11];
    const float* W2  = (const float*)d_in[12];
    const float* b2  = (const float*)d_in[13];
    const int*   ei  = (const int*)d_in[14];

    int n = in_sizes[0] / IN;
    int E = in_sizes[1];
    const int* src = ei;
    const int* dst = ei + E;

    float* h0    = (float*)d_ws;
    float* xr    = h0 + (size_t)n * HID;
    int*   cnt   = (int*)(xr + (size_t)n * HID);   // zeroed
    int*   off   = cnt + n;
    int*   bsum  = off + n;
    int*   boff  = bsum + 1024;
    int*   rank  = boff + 1024;
    int2*  csr   = (int2*)(rank + ((E + 1) & ~1));
    unsigned short* xlh = (unsigned short*)(csr + E);

    float* hout   = (float*)d_out;
    float* logits = hout + (size_t)n * HID;

    hipMemsetAsync(cnt, 0, (size_t)n * sizeof(int), stream);

    int rb = (n + 63) / 64;
    int nb = (n + 1023) / 1024;
    int Eb4 = (E / 4 + 255) / 256;

    k_pre_hist<<<rb + Eb4, 256, 0, stream>>>(x, Wp, h0, n, dst, cnt, rank, E, rb);
    k_lr_scan1<<<rb + nb, 256, 0, stream>>>(h0, Wl, bl, Wr, br, xr, xlh, n, cnt, off, bsum, rb);
    k_scan2<<<1, 1024, 0, stream>>>(bsum, boff, nb);
    k_scatter<<<Eb4, 256, 0, stream>>>(src, dst, ew, off, boff, rank, csr, E);
    k_agg <<<(n + 3) / 4, 256, 0, stream>>>(off, boff, csr, xlh, xr, h0, We, att, gb, hout, n, E);
    k_mlp <<<rb, 256, 0, stream>>>(hout, W1, b1, W2, b2, logits, n);
}

// Round 9
// 369.563 us; speedup vs baseline: 1.1658x; 1.0280x over previous
//
#include <hip/hip_runtime.h>
#include <hip/hip_bf16.h>
#include <math.h>

#define IN   128
#define HID  64
#define HEADS 4
#define NCLS 10

typedef __attribute__((ext_vector_type(8))) short bf16x8;
typedef __attribute__((ext_vector_type(4))) float f32x4;

__device__ __forceinline__ float lrelu02(float x) { return fmaxf(x, 0.2f * x); }

// f32 -> bf16 bits with round-to-nearest-even
__device__ __forceinline__ unsigned short f2bf(float f) {
    unsigned u = __float_as_uint(f);
    u += 0x7FFFu + ((u >> 16) & 1u);
    return (unsigned short)(u >> 16);
}
__device__ __forceinline__ float bf2f(unsigned short h) {
    return __uint_as_float((unsigned)h << 16);
}

template<int CTRL>
__device__ __forceinline__ float dppadd(float x) {
    int y = __builtin_amdgcn_update_dpp(0, __float_as_int(x), CTRL, 0xF, 0xF, true);
    return x + __int_as_float(y);
}
// sum over each 16-lane group (head): pure-VALU DPP tree
__device__ __forceinline__ float sum16(float p) {
    p = dppadd<0x128>(p);  // row_ror:8
    p = dppadd<0x124>(p);  // row_ror:4
    p = dppadd<0x4E>(p);   // quad_perm xor2
    p = dppadd<0xB1>(p);   // quad_perm xor1
    return p;
}

// ---------------- K1: h0 = x @ W_pre via MFMA bf16 (blocks < rb) + dst histogram (blocks >= rb) ----------------
// A layout: A[m=lane&15][k=(lane>>4)*8+j]; B layout: B[k=(lane>>4)*8+j][n=lane&15];
// C/D: col=lane&15, row=(lane>>4)*4+reg   [guide-verified m89/m91]
__global__ __launch_bounds__(256) void k_pre_hist(const float* __restrict__ x,
                                                  const float* __restrict__ Wp,
                                                  float* __restrict__ h0, int n,
                                                  const int* __restrict__ dst, int* __restrict__ cnt,
                                                  int* __restrict__ rank, int E, int rb)
{
    __shared__ unsigned short xb[64][136];   // bf16 x-tile, row pad 128->136 (bank decorrelate)
    __shared__ unsigned short wf[8192];      // Wp in MFMA b-fragment order
    int t = threadIdx.x;
    if ((int)blockIdx.x >= rb) {
        int e4 = (((int)blockIdx.x - rb) * 256 + t) * 4;
        if (e4 + 3 < E) {
            int4 d4 = *(const int4*)&dst[e4];
            int4 r4;
            r4.x = atomicAdd(&cnt[d4.x], 1);
            r4.y = atomicAdd(&cnt[d4.y], 1);
            r4.z = atomicAdd(&cnt[d4.z], 1);
            r4.w = atomicAdd(&cnt[d4.w], 1);
            *(int4*)&rank[e4] = r4;
        } else {
            for (int e = e4; e < E; e++) rank[e] = atomicAdd(&cnt[dst[e]], 1);
        }
        return;
    }

    // stage Wp (128x64 f32) -> wf bf16 fragment order: elem (k,nn) -> ((c*4+ks)*64 + l)*8 + j
    //   c=nn>>4, m=nn&15, ks=k>>5, quad=(k>>3)&3, j=k&7, l=m+16*quad
    for (int i = t; i < 2048; i += 256) {
        int k = i >> 4, n4 = (i & 15) * 4;
        float4 v = *(const float4*)&Wp[k * HID + n4];
        int ks = k >> 5, quad = (k >> 3) & 3, j = k & 7;
        int base = ks * 512 + (quad * 16) * 8 + j;   // ((c*4+ks)*64 + m+16q)*8+j with c,m folded below
        wf[base + (((n4 + 0) >> 4) * 2048) + ((n4 + 0) & 15) * 8] = f2bf(v.x);
        wf[base + (((n4 + 1) >> 4) * 2048) + ((n4 + 1) & 15) * 8] = f2bf(v.y);
        wf[base + (((n4 + 2) >> 4) * 2048) + ((n4 + 2) & 15) * 8] = f2bf(v.z);
        wf[base + (((n4 + 3) >> 4) * 2048) + ((n4 + 3) & 15) * 8] = f2bf(v.w);
    }
    // stage x tile (64 rows x 128) as bf16
    int row0 = blockIdx.x * 64;
    for (int i = t; i < 2048; i += 256) {
        int r = i >> 5, c4 = (i & 31) * 4;
        int row = row0 + r;
        float4 v = make_float4(0.f, 0.f, 0.f, 0.f);
        if (row < n) v = *(const float4*)&x[(size_t)row * IN + c4];
        ushort4 hb;
        hb.x = f2bf(v.x); hb.y = f2bf(v.y); hb.z = f2bf(v.z); hb.w = f2bf(v.w);
        *(ushort4*)&xb[r][c4] = hb;
    }
    __syncthreads();

    int wave = t >> 6, lane = t & 63;
    int m = lane & 15, quad = lane >> 4;
    int rbase = wave * 16;

    f32x4 acc0 = {0.f, 0.f, 0.f, 0.f};
    f32x4 acc1 = {0.f, 0.f, 0.f, 0.f};
    f32x4 acc2 = {0.f, 0.f, 0.f, 0.f};
    f32x4 acc3 = {0.f, 0.f, 0.f, 0.f};
    #pragma unroll
    for (int ks = 0; ks < 4; ks++) {
        bf16x8 a = *(const bf16x8*)&xb[rbase + m][ks * 32 + quad * 8];
        bf16x8 b0 = *(const bf16x8*)&wf[((0 * 4 + ks) * 64 + lane) * 8];
        bf16x8 b1 = *(const bf16x8*)&wf[((1 * 4 + ks) * 64 + lane) * 8];
        bf16x8 b2 = *(const bf16x8*)&wf[((2 * 4 + ks) * 64 + lane) * 8];
        bf16x8 b3 = *(const bf16x8*)&wf[((3 * 4 + ks) * 64 + lane) * 8];
        acc0 = __builtin_amdgcn_mfma_f32_16x16x32_bf16(a, b0, acc0, 0, 0, 0);
        acc1 = __builtin_amdgcn_mfma_f32_16x16x32_bf16(a, b1, acc1, 0, 0, 0);
        acc2 = __builtin_amdgcn_mfma_f32_16x16x32_bf16(a, b2, acc2, 0, 0, 0);
        acc3 = __builtin_amdgcn_mfma_f32_16x16x32_bf16(a, b3, acc3, 0, 0, 0);
    }
    #pragma unroll
    for (int r = 0; r < 4; r++) {
        int row = row0 + rbase + quad * 4 + r;
        if (row < n) {
            h0[(size_t)row * HID +  0 + m] = acc0[r];
            h0[(size_t)row * HID + 16 + m] = acc1[r];
            h0[(size_t)row * HID + 32 + m] = acc2[r];
            h0[(size_t)row * HID + 48 + m] = acc3[r];
        }
    }
}

// ---------------- K2: xl(bf16)/xr projections (blocks < rb) + scan stage1 (blocks >= rb) ----------------
__global__ __launch_bounds__(256) void k_lr_scan1(const float* __restrict__ h0,
                                                  const float* __restrict__ Wl, const float* __restrict__ bl,
                                                  const float* __restrict__ Wr, const float* __restrict__ br,
                                                  float* __restrict__ xr,
                                                  unsigned short* __restrict__ xlh, int n,
                                                  const int* __restrict__ cnt, int* __restrict__ off,
                                                  int* __restrict__ bsum, int rb)
{
    __shared__ float smem[12672];
    int t = threadIdx.x;

    if ((int)blockIdx.x >= rb) {
        int* si = (int*)smem;
        int bid = (int)blockIdx.x - rb;
        int base = bid * 1024 + t * 4;
        int c0 = 0, c1 = 0, c2 = 0, c3 = 0;
        if (base + 3 < n) {
            int4 c = *(const int4*)&cnt[base];
            c0 = c.x; c1 = c.y; c2 = c.z; c3 = c.w;
        } else {
            if (base     < n) c0 = cnt[base];
            if (base + 1 < n) c1 = cnt[base + 1];
            if (base + 2 < n) c2 = cnt[base + 2];
            if (base + 3 < n) c3 = cnt[base + 3];
        }
        int lsum = c0 + c1 + c2 + c3;
        si[t] = lsum;
        __syncthreads();
        for (int d = 1; d < 256; d <<= 1) {
            int add = (t >= d) ? si[t - d] : 0;
            __syncthreads();
            si[t] += add;
            __syncthreads();
        }
        int excl = si[t] - lsum;
        if (base     < n) off[base]     = excl;
        if (base + 1 < n) off[base + 1] = excl + c0;
        if (base + 2 < n) off[base + 2] = excl + c0 + c1;
        if (base + 3 < n) off[base + 3] = excl + c0 + c1 + c2;
        if (t == 255) bsum[bid] = si[255];
        return;
    }

    float* sWl = smem;
    float* sWr = smem + 4096;
    float* sh  = smem + 8192;
    float* sbl = smem + 12544;
    float* sbr = smem + 12608;
    for (int i = 4 * t; i < HID * HID; i += 1024) {
        *(float4*)&sWl[i] = *(const float4*)&Wl[i];
        *(float4*)&sWr[i] = *(const float4*)&Wr[i];
    }
    if (t < HID) { sbl[t] = bl[t]; sbr[t] = br[t]; }
    int row0 = blockIdx.x * 64;
    for (int i = t; i < 64 * (HID / 4); i += 256) {
        int r = i >> 4, c4 = (i & 15) * 4;
        int row = row0 + r;
        float4 v = make_float4(0.f, 0.f, 0.f, 0.f);
        if (row < n) v = *(const float4*)&h0[(size_t)row * HID + c4];
        *(float4*)&sh[r * 68 + c4] = v;
    }
    __syncthreads();
    int tc = t & 15, tr = t >> 4;
    int c0 = tc * 4, r0 = tr * 4;
    float accl[4][4] = {}, accr[4][4] = {};
    #pragma unroll 4
    for (int k = 0; k < HID; k++) {
        float4 wl = *(float4*)&sWl[k * HID + c0];
        float4 wr = *(float4*)&sWr[k * HID + c0];
        #pragma unroll
        for (int j = 0; j < 4; j++) {
            float hv = sh[(r0 + j) * 68 + k];
            accl[j][0] += hv * wl.x; accl[j][1] += hv * wl.y;
            accl[j][2] += hv * wl.z; accl[j][3] += hv * wl.w;
            accr[j][0] += hv * wr.x; accr[j][1] += hv * wr.y;
            accr[j][2] += hv * wr.z; accr[j][3] += hv * wr.w;
        }
    }
    float4 b4l = *(float4*)&sbl[c0];
    float4 b4r = *(float4*)&sbr[c0];
    #pragma unroll
    for (int j = 0; j < 4; j++) {
        int row = row0 + r0 + j;
        if (row < n) {
            ushort4 hb;
            hb.x = f2bf(accl[j][0] + b4l.x);
            hb.y = f2bf(accl[j][1] + b4l.y);
            hb.z = f2bf(accl[j][2] + b4l.z);
            hb.w = f2bf(accl[j][3] + b4l.w);
            *(ushort4*)&xlh[(size_t)row * HID + c0] = hb;
            *(float4*)&xr[(size_t)row * HID + c0] = make_float4(
                accr[j][0] + b4r.x, accr[j][1] + b4r.y, accr[j][2] + b4r.z, accr[j][3] + b4r.w);
        }
    }
}

// ---------------- Scan stage 2 ----------------
__global__ __launch_bounds__(1024) void k_scan2(const int* __restrict__ bsum, int* __restrict__ boff, int nb)
{
    __shared__ int s[1024];
    int i = threadIdx.x;
    int v = (i < nb) ? bsum[i] : 0;
    s[i] = v;
    __syncthreads();
    for (int d = 1; d < 1024; d <<= 1) {
        int add = (i >= d) ? s[i - d] : 0;
        __syncthreads();
        s[i] += add;
        __syncthreads();
    }
    if (i < nb) boff[i] = s[i] - v;
}

// ---------------- Scatter into CSR — atomic-free: pos = off[dst] + boff[dst>>10] + rank ----------------
__global__ __launch_bounds__(256) void k_scatter(const int* __restrict__ src, const int* __restrict__ dst,
                                                 const float* __restrict__ ew,
                                                 const int* __restrict__ off, const int* __restrict__ boff,
                                                 const int* __restrict__ rank,
                                                 int2* __restrict__ csr, int E)
{
    int e4 = (blockIdx.x * 256 + threadIdx.x) * 4;
    if (e4 + 3 < E) {
        int4   s4 = *(const int4*)&src[e4];
        int4   d4 = *(const int4*)&dst[e4];
        int4   r4 = *(const int4*)&rank[e4];
        float4 w4 = *(const float4*)&ew[e4];
        int p0 = off[d4.x] + boff[d4.x >> 10] + r4.x;
        int p1 = off[d4.y] + boff[d4.y >> 10] + r4.y;
        int p2 = off[d4.z] + boff[d4.z >> 10] + r4.z;
        int p3 = off[d4.w] + boff[d4.w >> 10] + r4.w;
        csr[p0] = make_int2(s4.x, __float_as_int(w4.x));
        csr[p1] = make_int2(s4.y, __float_as_int(w4.y));
        csr[p2] = make_int2(s4.z, __float_as_int(w4.z));
        csr[p3] = make_int2(s4.w, __float_as_int(w4.w));
    } else {
        for (int e = e4; e < E; e++) {
            int p = off[dst[e]] + boff[dst[e] >> 10] + rank[e];
            csr[p] = make_int2(src[e], __float_as_int(ew[e]));
        }
    }
}

// ---------------- K_agg: one wave per dst; bf16 gathers; unguarded 8-deep pipeline; DPP + exp2 ----------------
__global__ __launch_bounds__(256) void k_agg(const int* __restrict__ off, const int* __restrict__ boff,
                                             const int2* __restrict__ csr,
                                             const unsigned short* __restrict__ xlh,
                                             const float* __restrict__ xr,
                                             const float* __restrict__ h0,
                                             const float* __restrict__ We, const float* __restrict__ att,
                                             const float* __restrict__ gb,
                                             float* __restrict__ hout, int n, int E)
{
    __shared__ float sWe[HID], sAtt[HID], sGb[HID];
    int t = threadIdx.x;
    if (t < HID) {
        sWe[t] = We[t];
        sAtt[t] = att[t] * 1.44269504f;   // pre-scale by log2(e)
        sGb[t] = gb[t];
    }
    __syncthreads();
    int lane = t & 63;
    int v = blockIdx.x * 4 + (t >> 6);
    if (v >= n) return;

    int beg = off[v] + boff[v >> 10];
    int end = (v == n - 1) ? E : off[v + 1] + boff[(v + 1) >> 10];

    float we = sWe[lane], at = sAtt[lane];
    float xrv = xr[(size_t)v * HID + lane];
    float xlv = bf2f(xlh[((size_t)v << 6) + lane]);

    float num = 0.f, den = 0.f, wsum = 0.f;

    for (int base = beg; base < end; base += 64) {
        int m = end - base; if (m > 64) m = 64;
        int sv = 0, wvb = 0;
        if (lane < m) {
            int2 cw = csr[base + lane];
            sv = cw.x;
            wvb = cw.y;
        }
        int m8 = m & ~7;
        int j0 = 0;
        for (; j0 < m8; j0 += 8) {
            float xls[8], wj[8];
            #pragma unroll
            for (int u = 0; u < 8; u++) {
                int ss = __builtin_amdgcn_readlane(sv, j0 + u);
                int wb = __builtin_amdgcn_readlane(wvb, j0 + u);
                wj[u] = __int_as_float(wb);
                const unsigned short* ph = xlh + ((unsigned)ss << 6);
                xls[u] = bf2f(ph[lane]);
            }
            #pragma unroll
            for (int u = 0; u < 8; u++) {
                float ef = lrelu02(xls[u] + xrv + wj[u] * we);
                float p = sum16(ef * at);
                float ex = __builtin_amdgcn_exp2f(p);
                num += ex * xls[u];
                den += ex;
                wsum += wj[u];
            }
        }
        for (; j0 < m; j0++) {
            int ss = __builtin_amdgcn_readlane(sv, j0);
            int wb = __builtin_amdgcn_readlane(wvb, j0);
            float w = __int_as_float(wb);
            float xls = bf2f(xlh[((unsigned)ss << 6) + lane]);
            float ef = lrelu02(xls + xrv + w * we);
            float p = sum16(ef * at);
            float ex = __builtin_amdgcn_exp2f(p);
            num += ex * xls;
            den += ex;
            wsum += w;
        }
    }

    // analytic self-loop
    float cntf = (float)(end - beg);
    float la = wsum / fmaxf(cntf, 1.0f);
    float ef = lrelu02(xlv + xrv + la * we);
    float p = sum16(ef * at);
    float exs = __builtin_amdgcn_exp2f(p);
    den += exs;
    num += exs * xlv;

    float o = num / den + sGb[lane];
    float h1 = o > 0.f ? o : expm1f(o);
    hout[(size_t)v * HID + lane] = h0[(size_t)v * HID + lane] + h1;
}

// ---------------- K_mlp: logits = relu(h@W1+b1)@W2+b2 ----------------
__global__ __launch_bounds__(256) void k_mlp(const float* __restrict__ h,
                                             const float* __restrict__ W1, const float* __restrict__ b1,
                                             const float* __restrict__ W2, const float* __restrict__ b2,
                                             float* __restrict__ logits, int n)
{
    __shared__ float sW1[HID * HID];
    __shared__ float sh[64][HID + 4];
    __shared__ float sz[64][HID + 4];
    __shared__ float sW2[HID * NCLS];
    __shared__ float sb1[HID], sb2[NCLS];
    int t = threadIdx.x;
    for (int i = 4 * t; i < HID * HID; i += 1024)
        *(float4*)&sW1[i] = *(const float4*)&W1[i];
    if (4 * t < HID * NCLS)
        *(float4*)&sW2[4 * t] = *(const float4*)&W2[4 * t];
    if (t < HID)  sb1[t] = b1[t];
    if (t < NCLS) sb2[t] = b2[t];
    int row0 = blockIdx.x * 64;
    for (int i = t; i < 64 * (HID / 4); i += 256) {
        int r = i >> 4, c4 = (i & 15) * 4;
        int row = row0 + r;
        float4 v = make_float4(0.f, 0.f, 0.f, 0.f);
        if (row < n) v = *(const float4*)&h[(size_t)row * HID + c4];
        *(float4*)&sh[r][c4] = v;
    }
    __syncthreads();
    int tc = t & 15, tr = t >> 4;
    int c0 = tc * 4, r0 = tr * 4;
    float4 b14 = *(float4*)&sb1[c0];
    float acc[4][4];
    #pragma unroll
    for (int j = 0; j < 4; j++) { acc[j][0] = b14.x; acc[j][1] = b14.y; acc[j][2] = b14.z; acc[j][3] = b14.w; }
    #pragma unroll 4
    for (int k = 0; k < HID; k++) {
        float4 w = *(float4*)&sW1[k * HID + c0];
        #pragma unroll
        for (int j = 0; j < 4; j++) {
            float hv = sh[r0 + j][k];
            acc[j][0] += hv * w.x; acc[j][1] += hv * w.y;
            acc[j][2] += hv * w.z; acc[j][3] += hv * w.w;
        }
    }
    #pragma unroll
    for (int j = 0; j < 4; j++) {
        sz[r0 + j][c0 + 0] = fmaxf(acc[j][0], 0.f);
        sz[r0 + j][c0 + 1] = fmaxf(acc[j][1], 0.f);
        sz[r0 + j][c0 + 2] = fmaxf(acc[j][2], 0.f);
        sz[r0 + j][c0 + 3] = fmaxf(acc[j][3], 0.f);
    }
    __syncthreads();
    for (int i = t; i < 64 * NCLS; i += 256) {
        int r = i / NCLS, c = i - r * NCLS;
        int row = row0 + r;
        float s = sb2[c];
        #pragma unroll 8
        for (int k = 0; k < HID; k++) s += sz[r][k] * sW2[k * NCLS + c];
        if (row < n) logits[(size_t)row * NCLS + c] = s;
    }
}

extern "C" void kernel_launch(void* const* d_in, const int* in_sizes, int n_in,
                              void* d_out, int out_size, void* d_ws, size_t ws_size,
                              hipStream_t stream)
{
    const float* x   = (const float*)d_in[0];
    const float* ew  = (const float*)d_in[1];
    const float* Wp  = (const float*)d_in[2];
    const float* Wl  = (const float*)d_in[3];
    const float* bl  = (const float*)d_in[4];
    const float* Wr  = (const float*)d_in[5];
    const float* br  = (const float*)d_in[6];
    const float* att = (const float*)d_in[7];
    const float* We  = (const float*)d_in[8];
    const float* gb  = (const float*)d_in[9];
    const float* W1  = (const float*)d_in[10];
    const float* b1  = (const float*)d_in[11];
    const float* W2  = (const float*)d_in[12];
    const float* b2  = (const float*)d_in[13];
    const int*   ei  = (const int*)d_in[14];

    int n = in_sizes[0] / IN;
    int E = in_sizes[1];
    const int* src = ei;
    const int* dst = ei + E;

    float* h0    = (float*)d_ws;
    float* xr    = h0 + (size_t)n * HID;
    int*   cnt   = (int*)(xr + (size_t)n * HID);   // zeroed
    int*   off   = cnt + n;
    int*   bsum  = off + n;
    int*   boff  = bsum + 1024;
    int*   rank  = boff + 1024;
    int2*  csr   = (int2*)(rank + ((E + 1) & ~1));
    unsigned short* xlh = (unsigned short*)(csr + E);

    float* hout   = (float*)d_out;
    float* logits = hout + (size_t)n * HID;

    hipMemsetAsync(cnt, 0, (size_t)n * sizeof(int), stream);

    int rb = (n + 63) / 64;
    int nb = (n + 1023) / 1024;
    int Eb4 = (E / 4 + 255) / 256;

    k_pre_hist<<<rb + Eb4, 256, 0, stream>>>(x, Wp, h0, n, dst, cnt, rank, E, rb);
    k_lr_scan1<<<rb + nb, 256, 0, stream>>>(h0, Wl, bl, Wr, br, xr, xlh, n, cnt, off, bsum, rb);
    k_scan2<<<1, 1024, 0, stream>>>(bsum, boff, nb);
    k_scatter<<<Eb4, 256, 0, stream>>>(src, dst, ew, off, boff, rank, csr, E);
    k_agg <<<(n + 3) / 4, 256, 0, stream>>>(off, boff, csr, xlh, xr, h0, We, att, gb, hout, n, E);
    k_mlp <<<rb, 256, 0, stream>>>(hout, W1, b1, W2, b2, logits, n);
}

// Round 10
// 362.785 us; speedup vs baseline: 1.1876x; 1.0187x over previous
//
#include <hip/hip_runtime.h>
#include <hip/hip_bf16.h>
#include <math.h>

#define IN   128
#define HID  64
#define HEADS 4
#define NCLS 10

typedef __attribute__((ext_vector_type(8))) short bf16x8;
typedef __attribute__((ext_vector_type(4))) float f32x4;

__device__ __forceinline__ float lrelu02(float x) { return fmaxf(x, 0.2f * x); }

// f32 -> bf16 bits with round-to-nearest-even
__device__ __forceinline__ unsigned short f2bf(float f) {
    unsigned u = __float_as_uint(f);
    u += 0x7FFFu + ((u >> 16) & 1u);
    return (unsigned short)(u >> 16);
}
__device__ __forceinline__ float bf2f(unsigned short h) {
    return __uint_as_float((unsigned)h << 16);
}

template<int CTRL>
__device__ __forceinline__ float dppadd(float x) {
    int y = __builtin_amdgcn_update_dpp(0, __float_as_int(x), CTRL, 0xF, 0xF, true);
    return x + __int_as_float(y);
}
// sum over each 16-lane group (head): pure-VALU DPP tree
__device__ __forceinline__ float sum16(float p) {
    p = dppadd<0x128>(p);  // row_ror:8
    p = dppadd<0x124>(p);  // row_ror:4
    p = dppadd<0x4E>(p);   // quad_perm xor2
    p = dppadd<0xB1>(p);   // quad_perm xor1
    return p;
}

// ---------------- K0: dst histogram w/ rank capture ----------------
__global__ __launch_bounds__(256) void k_hist(const int* __restrict__ dst, int* __restrict__ cnt,
                                              int* __restrict__ rank, int E)
{
    int e4 = (blockIdx.x * 256 + threadIdx.x) * 4;
    if (e4 + 3 < E) {
        int4 d4 = *(const int4*)&dst[e4];
        int4 r4;
        r4.x = atomicAdd(&cnt[d4.x], 1);
        r4.y = atomicAdd(&cnt[d4.y], 1);
        r4.z = atomicAdd(&cnt[d4.z], 1);
        r4.w = atomicAdd(&cnt[d4.w], 1);
        *(int4*)&rank[e4] = r4;
    } else {
        for (int e = e4; e < E; e++) rank[e] = atomicAdd(&cnt[dst[e]], 1);
    }
}

// ---------------- K1: h0 (bf16) = x @ W_pre via MFMA ----------------
// A[m=lane&15][k=quad*8+j]; B[k=quad*8+j][n=lane&15]; C/D col=lane&15,row=quad*4+reg
__global__ __launch_bounds__(256) void k_pre(const float* __restrict__ x,
                                             const float* __restrict__ Wp,
                                             unsigned short* __restrict__ h0h, int n)
{
    __shared__ unsigned short xb[64][136];   // bf16 x-tile (17.4 KB); reused as f32 64x66 scratch
    __shared__ unsigned short wf[8192];      // Wp in MFMA b-fragment order (16 KB)
    int t = threadIdx.x;

    // stage Wp -> fragment order; each thread writes contiguous 16B chunks (conflict-free)
    // w = ((c*4+ks)*64 + q*16+m)*8 + j ; element = Wp[(ks*32+q*8+j)*64 + c*16+m]
    for (int w0 = t * 8; w0 < 8192; w0 += 2048) {
        int c  = w0 >> 11;
        int ks = (w0 >> 9) & 3;
        int lp = (w0 >> 3) & 63;
        int q = lp >> 4, m = lp & 15;
        int nn = c * 16 + m;
        int kb = ks * 32 + q * 8;
        ushort4 a, b;
        a.x = f2bf(Wp[(kb + 0) * HID + nn]);
        a.y = f2bf(Wp[(kb + 1) * HID + nn]);
        a.z = f2bf(Wp[(kb + 2) * HID + nn]);
        a.w = f2bf(Wp[(kb + 3) * HID + nn]);
        b.x = f2bf(Wp[(kb + 4) * HID + nn]);
        b.y = f2bf(Wp[(kb + 5) * HID + nn]);
        b.z = f2bf(Wp[(kb + 6) * HID + nn]);
        b.w = f2bf(Wp[(kb + 7) * HID + nn]);
        *(ushort4*)&wf[w0]     = a;
        *(ushort4*)&wf[w0 + 4] = b;
    }
    // stage x tile (64 x 128) as bf16
    int row0 = blockIdx.x * 64;
    for (int i = t; i < 2048; i += 256) {
        int r = i >> 5, c4 = (i & 31) * 4;
        int row = row0 + r;
        float4 v = make_float4(0.f, 0.f, 0.f, 0.f);
        if (row < n) v = *(const float4*)&x[(size_t)row * IN + c4];
        ushort4 hb;
        hb.x = f2bf(v.x); hb.y = f2bf(v.y); hb.z = f2bf(v.z); hb.w = f2bf(v.w);
        *(ushort4*)&xb[r][c4] = hb;
    }
    __syncthreads();

    int wave = t >> 6, lane = t & 63;
    int m = lane & 15, quad = lane >> 4;
    int rbase = wave * 16;

    f32x4 acc0 = {0.f, 0.f, 0.f, 0.f};
    f32x4 acc1 = {0.f, 0.f, 0.f, 0.f};
    f32x4 acc2 = {0.f, 0.f, 0.f, 0.f};
    f32x4 acc3 = {0.f, 0.f, 0.f, 0.f};
    #pragma unroll
    for (int ks = 0; ks < 4; ks++) {
        bf16x8 a = *(const bf16x8*)&xb[rbase + m][ks * 32 + quad * 8];
        bf16x8 b0 = *(const bf16x8*)&wf[((0 * 4 + ks) * 64 + lane) * 8];
        bf16x8 b1 = *(const bf16x8*)&wf[((1 * 4 + ks) * 64 + lane) * 8];
        bf16x8 b2 = *(const bf16x8*)&wf[((2 * 4 + ks) * 64 + lane) * 8];
        bf16x8 b3 = *(const bf16x8*)&wf[((3 * 4 + ks) * 64 + lane) * 8];
        acc0 = __builtin_amdgcn_mfma_f32_16x16x32_bf16(a, b0, acc0, 0, 0, 0);
        acc1 = __builtin_amdgcn_mfma_f32_16x16x32_bf16(a, b1, acc1, 0, 0, 0);
        acc2 = __builtin_amdgcn_mfma_f32_16x16x32_bf16(a, b2, acc2, 0, 0, 0);
        acc3 = __builtin_amdgcn_mfma_f32_16x16x32_bf16(a, b3, acc3, 0, 0, 0);
    }
    __syncthreads();   // xb reads complete; reuse as f32 scratch
    float* sc = (float*)&xb[0][0];   // 64 x 66
    #pragma unroll
    for (int r = 0; r < 4; r++) {
        int lrow = rbase + quad * 4 + r;
        sc[lrow * 66 +  0 + m] = acc0[r];
        sc[lrow * 66 + 16 + m] = acc1[r];
        sc[lrow * 66 + 32 + m] = acc2[r];
        sc[lrow * 66 + 48 + m] = acc3[r];
    }
    __syncthreads();
    for (int i = t; i < 1024; i += 256) {
        int r = i >> 4, c4 = (i & 15) * 4;
        int row = row0 + r;
        if (row < n) {
            ushort4 hb;
            hb.x = f2bf(sc[r * 66 + c4 + 0]);
            hb.y = f2bf(sc[r * 66 + c4 + 1]);
            hb.z = f2bf(sc[r * 66 + c4 + 2]);
            hb.w = f2bf(sc[r * 66 + c4 + 3]);
            *(ushort4*)&h0h[(size_t)row * HID + c4] = hb;
        }
    }
}

// ---------------- K2: xl/xr (bf16) = h0 @ {Wl,Wr} + b via MFMA (blocks < rb) + scan1 (blocks >= rb) ----------------
__global__ __launch_bounds__(256) void k_lr_scan1(const unsigned short* __restrict__ h0h,
                                                  const float* __restrict__ Wl, const float* __restrict__ bl,
                                                  const float* __restrict__ Wr, const float* __restrict__ br,
                                                  unsigned short* __restrict__ xlh,
                                                  unsigned short* __restrict__ xrh, int n,
                                                  const int* __restrict__ cnt, int* __restrict__ off,
                                                  int* __restrict__ bsum, int rb)
{
    __shared__ unsigned short wfL[4096];     // 8 KB  fragment-ordered Wl
    __shared__ unsigned short wfR[4096];     // 8 KB  fragment-ordered Wr
    __shared__ unsigned short hb[64][72];    // 9.2 KB bf16 h-tile; reused as f32 32x66 scratch
    __shared__ float sbl[64], sbr[64];
    int t = threadIdx.x;

    if ((int)blockIdx.x >= rb) {
        // ---- scan1: 256 threads scan 1024 counts ----
        int* si = (int*)wfL;
        int bid = (int)blockIdx.x - rb;
        int base = bid * 1024 + t * 4;
        int c0 = 0, c1 = 0, c2 = 0, c3 = 0;
        if (base + 3 < n) {
            int4 c = *(const int4*)&cnt[base];
            c0 = c.x; c1 = c.y; c2 = c.z; c3 = c.w;
        } else {
            if (base     < n) c0 = cnt[base];
            if (base + 1 < n) c1 = cnt[base + 1];
            if (base + 2 < n) c2 = cnt[base + 2];
            if (base + 3 < n) c3 = cnt[base + 3];
        }
        int lsum = c0 + c1 + c2 + c3;
        si[t] = lsum;
        __syncthreads();
        for (int d = 1; d < 256; d <<= 1) {
            int add = (t >= d) ? si[t - d] : 0;
            __syncthreads();
            si[t] += add;
            __syncthreads();
        }
        int excl = si[t] - lsum;
        if (base     < n) off[base]     = excl;
        if (base + 1 < n) off[base + 1] = excl + c0;
        if (base + 2 < n) off[base + 2] = excl + c0 + c1;
        if (base + 3 < n) off[base + 3] = excl + c0 + c1 + c2;
        if (t == 255) bsum[bid] = si[255];
        return;
    }

    // stage Wl/Wr -> fragment order (K=64: ks in {0,1}); contiguous 16B writes
    // w = ((c*2+ks)*64 + q*16+m)*8 + j ; element = W[(ks*32+q*8+j)*64 + c*16+m]
    for (int w0 = t * 8; w0 < 4096; w0 += 2048) {
        int c  = w0 >> 10;
        int ks = (w0 >> 9) & 1;
        int lp = (w0 >> 3) & 63;
        int q = lp >> 4, m = lp & 15;
        int nn = c * 16 + m;
        int kb = ks * 32 + q * 8;
        ushort4 a, b;
        a.x = f2bf(Wl[(kb + 0) * HID + nn]);
        a.y = f2bf(Wl[(kb + 1) * HID + nn]);
        a.z = f2bf(Wl[(kb + 2) * HID + nn]);
        a.w = f2bf(Wl[(kb + 3) * HID + nn]);
        b.x = f2bf(Wl[(kb + 4) * HID + nn]);
        b.y = f2bf(Wl[(kb + 5) * HID + nn]);
        b.z = f2bf(Wl[(kb + 6) * HID + nn]);
        b.w = f2bf(Wl[(kb + 7) * HID + nn]);
        *(ushort4*)&wfL[w0]     = a;
        *(ushort4*)&wfL[w0 + 4] = b;
        a.x = f2bf(Wr[(kb + 0) * HID + nn]);
        a.y = f2bf(Wr[(kb + 1) * HID + nn]);
        a.z = f2bf(Wr[(kb + 2) * HID + nn]);
        a.w = f2bf(Wr[(kb + 3) * HID + nn]);
        b.x = f2bf(Wr[(kb + 4) * HID + nn]);
        b.y = f2bf(Wr[(kb + 5) * HID + nn]);
        b.z = f2bf(Wr[(kb + 6) * HID + nn]);
        b.w = f2bf(Wr[(kb + 7) * HID + nn]);
        *(ushort4*)&wfR[w0]     = a;
        *(ushort4*)&wfR[w0 + 4] = b;
    }
    if (t < 64) { sbl[t] = bl[t]; sbr[t] = br[t]; }
    // stage h tile (64 x 64 bf16)
    int row0 = blockIdx.x * 64;
    for (int i = t; i < 1024; i += 256) {
        int r = i >> 4, c4 = (i & 15) * 4;
        int row = row0 + r;
        ushort4 v = make_ushort4(0, 0, 0, 0);
        if (row < n) v = *(const ushort4*)&h0h[(size_t)row * HID + c4];
        *(ushort4*)&hb[r][c4] = v;
    }
    __syncthreads();

    int wave = t >> 6, lane = t & 63;
    int m = lane & 15, quad = lane >> 4;
    int rbase = wave * 16;

    f32x4 aL0 = {0,0,0,0}, aL1 = {0,0,0,0}, aL2 = {0,0,0,0}, aL3 = {0,0,0,0};
    f32x4 aR0 = {0,0,0,0}, aR1 = {0,0,0,0}, aR2 = {0,0,0,0}, aR3 = {0,0,0,0};
    #pragma unroll
    for (int ks = 0; ks < 2; ks++) {
        bf16x8 a = *(const bf16x8*)&hb[rbase + m][ks * 32 + quad * 8];
        bf16x8 bL0 = *(const bf16x8*)&wfL[((0 * 2 + ks) * 64 + lane) * 8];
        bf16x8 bL1 = *(const bf16x8*)&wfL[((1 * 2 + ks) * 64 + lane) * 8];
        bf16x8 bL2 = *(const bf16x8*)&wfL[((2 * 2 + ks) * 64 + lane) * 8];
        bf16x8 bL3 = *(const bf16x8*)&wfL[((3 * 2 + ks) * 64 + lane) * 8];
        aL0 = __builtin_amdgcn_mfma_f32_16x16x32_bf16(a, bL0, aL0, 0, 0, 0);
        aL1 = __builtin_amdgcn_mfma_f32_16x16x32_bf16(a, bL1, aL1, 0, 0, 0);
        aL2 = __builtin_amdgcn_mfma_f32_16x16x32_bf16(a, bL2, aL2, 0, 0, 0);
        aL3 = __builtin_amdgcn_mfma_f32_16x16x32_bf16(a, bL3, aL3, 0, 0, 0);
        bf16x8 bR0 = *(const bf16x8*)&wfR[((0 * 2 + ks) * 64 + lane) * 8];
        bf16x8 bR1 = *(const bf16x8*)&wfR[((1 * 2 + ks) * 64 + lane) * 8];
        bf16x8 bR2 = *(const bf16x8*)&wfR[((2 * 2 + ks) * 64 + lane) * 8];
        bf16x8 bR3 = *(const bf16x8*)&wfR[((3 * 2 + ks) * 64 + lane) * 8];
        aR0 = __builtin_amdgcn_mfma_f32_16x16x32_bf16(a, bR0, aR0, 0, 0, 0);
        aR1 = __builtin_amdgcn_mfma_f32_16x16x32_bf16(a, bR1, aR1, 0, 0, 0);
        aR2 = __builtin_amdgcn_mfma_f32_16x16x32_bf16(a, bR2, aR2, 0, 0, 0);
        aR3 = __builtin_amdgcn_mfma_f32_16x16x32_bf16(a, bR3, aR3, 0, 0, 0);
    }
    // add biases: acc c covers out col c*16+m
    float bL[4] = { sbl[m], sbl[16 + m], sbl[32 + m], sbl[48 + m] };
    float bR[4] = { sbr[m], sbr[16 + m], sbr[32 + m], sbr[48 + m] };
    #pragma unroll
    for (int r = 0; r < 4; r++) {
        aL0[r] += bL[0]; aL1[r] += bL[1]; aL2[r] += bL[2]; aL3[r] += bL[3];
        aR0[r] += bR[0]; aR1[r] += bR[1]; aR2[r] += bR[2]; aR3[r] += bR[3];
    }
    __syncthreads();   // hb reads complete; reuse as f32 scratch (32 x 66)
    float* sc = (float*)&hb[0][0];

    // 4 transpose passes: {L,half0},{L,half1},{R,half0},{R,half1}
    #pragma unroll
    for (int pass = 0; pass < 4; pass++) {
        int half = pass & 1;
        bool isL = pass < 2;
        if ((wave >> 1) == half) {           // waves 0,1 -> rows 0..31 ; waves 2,3 -> 32..63
            int lrow = (rbase & 31) + quad * 4;
            f32x4 c0 = isL ? aL0 : aR0, c1 = isL ? aL1 : aR1;
            f32x4 c2 = isL ? aL2 : aR2, c3 = isL ? aL3 : aR3;
            #pragma unroll
            for (int r = 0; r < 4; r++) {
                sc[(lrow + r) * 66 +  0 + m] = c0[r];
                sc[(lrow + r) * 66 + 16 + m] = c1[r];
                sc[(lrow + r) * 66 + 32 + m] = c2[r];
                sc[(lrow + r) * 66 + 48 + m] = c3[r];
            }
        }
        __syncthreads();
        unsigned short* dst = isL ? xlh : xrh;
        for (int i = t; i < 512; i += 256) {
            int r = i >> 4, c4 = (i & 15) * 4;
            int row = row0 + half * 32 + r;
            if (row < n) {
                ushort4 hv;
                hv.x = f2bf(sc[r * 66 + c4 + 0]);
                hv.y = f2bf(sc[r * 66 + c4 + 1]);
                hv.z = f2bf(sc[r * 66 + c4 + 2]);
                hv.w = f2bf(sc[r * 66 + c4 + 3]);
                *(ushort4*)&dst[(size_t)row * HID + c4] = hv;
            }
        }
        __syncthreads();
    }
}

// ---------------- Scan stage 2 ----------------
__global__ __launch_bounds__(1024) void k_scan2(const int* __restrict__ bsum, int* __restrict__ boff, int nb)
{
    __shared__ int s[1024];
    int i = threadIdx.x;
    int v = (i < nb) ? bsum[i] : 0;
    s[i] = v;
    __syncthreads();
    for (int d = 1; d < 1024; d <<= 1) {
        int add = (i >= d) ? s[i - d] : 0;
        __syncthreads();
        s[i] += add;
        __syncthreads();
    }
    if (i < nb) boff[i] = s[i] - v;
}

// ---------------- Scatter into CSR — atomic-free: pos = off[dst] + boff[dst>>10] + rank ----------------
__global__ __launch_bounds__(256) void k_scatter(const int* __restrict__ src, const int* __restrict__ dst,
                                                 const float* __restrict__ ew,
                                                 const int* __restrict__ off, const int* __restrict__ boff,
                                                 const int* __restrict__ rank,
                                                 int2* __restrict__ csr, int E)
{
    int e4 = (blockIdx.x * 256 + threadIdx.x) * 4;
    if (e4 + 3 < E) {
        int4   s4 = *(const int4*)&src[e4];
        int4   d4 = *(const int4*)&dst[e4];
        int4   r4 = *(const int4*)&rank[e4];
        float4 w4 = *(const float4*)&ew[e4];
        int p0 = off[d4.x] + boff[d4.x >> 10] + r4.x;
        int p1 = off[d4.y] + boff[d4.y >> 10] + r4.y;
        int p2 = off[d4.z] + boff[d4.z >> 10] + r4.z;
        int p3 = off[d4.w] + boff[d4.w >> 10] + r4.w;
        csr[p0] = make_int2(s4.x, __float_as_int(w4.x));
        csr[p1] = make_int2(s4.y, __float_as_int(w4.y));
        csr[p2] = make_int2(s4.z, __float_as_int(w4.z));
        csr[p3] = make_int2(s4.w, __float_as_int(w4.w));
    } else {
        for (int e = e4; e < E; e++) {
            int p = off[dst[e]] + boff[dst[e] >> 10] + rank[e];
            csr[p] = make_int2(src[e], __float_as_int(ew[e]));
        }
    }
}

// ---------------- K_agg: one wave per dst; bf16 gathers; unguarded 8-deep pipeline; DPP + exp2 ----------------
__global__ __launch_bounds__(256) void k_agg(const int* __restrict__ off, const int* __restrict__ boff,
                                             const int2* __restrict__ csr,
                                             const unsigned short* __restrict__ xlh,
                                             const unsigned short* __restrict__ xrh,
                                             const unsigned short* __restrict__ h0h,
                                             const float* __restrict__ We, const float* __restrict__ att,
                                             const float* __restrict__ gb,
                                             float* __restrict__ hout, int n, int E)
{
    __shared__ float sWe[HID], sAtt[HID], sGb[HID];
    int t = threadIdx.x;
    if (t < HID) {
        sWe[t] = We[t];
        sAtt[t] = att[t] * 1.44269504f;   // pre-scale by log2(e)
        sGb[t] = gb[t];
    }
    __syncthreads();
    int lane = t & 63;
    int v = blockIdx.x * 4 + (t >> 6);
    if (v >= n) return;

    int beg = off[v] + boff[v >> 10];
    int end = (v == n - 1) ? E : off[v + 1] + boff[(v + 1) >> 10];

    float we = sWe[lane], at = sAtt[lane];
    float xrv = bf2f(xrh[((size_t)v << 6) + lane]);
    float xlv = bf2f(xlh[((size_t)v << 6) + lane]);

    float num = 0.f, den = 0.f, wsum = 0.f;

    for (int base = beg; base < end; base += 64) {
        int m = end - base; if (m > 64) m = 64;
        int sv = 0, wvb = 0;
        if (lane < m) {
            int2 cw = csr[base + lane];
            sv = cw.x;
            wvb = cw.y;
        }
        int m8 = m & ~7;
        int j0 = 0;
        for (; j0 < m8; j0 += 8) {
            float xls[8], wj[8];
            #pragma unroll
            for (int u = 0; u < 8; u++) {
                int ss = __builtin_amdgcn_readlane(sv, j0 + u);
                int wb = __builtin_amdgcn_readlane(wvb, j0 + u);
                wj[u] = __int_as_float(wb);
                const unsigned short* ph = xlh + ((unsigned)ss << 6);
                xls[u] = bf2f(ph[lane]);
            }
            #pragma unroll
            for (int u = 0; u < 8; u++) {
                float ef = lrelu02(xls[u] + xrv + wj[u] * we);
                float p = sum16(ef * at);
                float ex = __builtin_amdgcn_exp2f(p);
                num += ex * xls[u];
                den += ex;
                wsum += wj[u];
            }
        }
        for (; j0 < m; j0++) {
            int ss = __builtin_amdgcn_readlane(sv, j0);
            int wb = __builtin_amdgcn_readlane(wvb, j0);
            float w = __int_as_float(wb);
            float xls = bf2f(xlh[((unsigned)ss << 6) + lane]);
            float ef = lrelu02(xls + xrv + w * we);
            float p = sum16(ef * at);
            float ex = __builtin_amdgcn_exp2f(p);
            num += ex * xls;
            den += ex;
            wsum += w;
        }
    }

    // analytic self-loop
    float cntf = (float)(end - beg);
    float la = wsum / fmaxf(cntf, 1.0f);
    float ef = lrelu02(xlv + xrv + la * we);
    float p = sum16(ef * at);
    float exs = __builtin_amdgcn_exp2f(p);
    den += exs;
    num += exs * xlv;

    float o = num / den + sGb[lane];
    float h1 = o > 0.f ? o : expm1f(o);
    hout[(size_t)v * HID + lane] = bf2f(h0h[((size_t)v << 6) + lane]) + h1;
}

// ---------------- K_mlp: logits = relu(h@W1+b1)@W2+b2 ----------------
__global__ __launch_bounds__(256) void k_mlp(const float* __restrict__ h,
                                             const float* __restrict__ W1, const float* __restrict__ b1,
                                             const float* __restrict__ W2, const float* __restrict__ b2,
                                             float* __restrict__ logits, int n)
{
    __shared__ float sW1[HID * HID];
    __shared__ float sh[64][HID + 4];
    __shared__ float sz[64][HID + 4];
    __shared__ float sW2[HID * NCLS];
    __shared__ float sb1[HID], sb2[NCLS];
    int t = threadIdx.x;
    for (int i = 4 * t; i < HID * HID; i += 1024)
        *(float4*)&sW1[i] = *(const float4*)&W1[i];
    if (4 * t < HID * NCLS)
        *(float4*)&sW2[4 * t] = *(const float4*)&W2[4 * t];
    if (t < HID)  sb1[t] = b1[t];
    if (t < NCLS) sb2[t] = b2[t];
    int row0 = blockIdx.x * 64;
    for (int i = t; i < 64 * (HID / 4); i += 256) {
        int r = i >> 4, c4 = (i & 15) * 4;
        int row = row0 + r;
        float4 v = make_float4(0.f, 0.f, 0.f, 0.f);
        if (row < n) v = *(const float4*)&h[(size_t)row * HID + c4];
        *(float4*)&sh[r][c4] = v;
    }
    __syncthreads();
    int tc = t & 15, tr = t >> 4;
    int c0 = tc * 4, r0 = tr * 4;
    float4 b14 = *(float4*)&sb1[c0];
    float acc[4][4];
    #pragma unroll
    for (int j = 0; j < 4; j++) { acc[j][0] = b14.x; acc[j][1] = b14.y; acc[j][2] = b14.z; acc[j][3] = b14.w; }
    #pragma unroll 4
    for (int k = 0; k < HID; k++) {
        float4 w = *(float4*)&sW1[k * HID + c0];
        #pragma unroll
        for (int j = 0; j < 4; j++) {
            float hv = sh[r0 + j][k];
            acc[j][0] += hv * w.x; acc[j][1] += hv * w.y;
            acc[j][2] += hv * w.z; acc[j][3] += hv * w.w;
        }
    }
    #pragma unroll
    for (int j = 0; j < 4; j++) {
        sz[r0 + j][c0 + 0] = fmaxf(acc[j][0], 0.f);
        sz[r0 + j][c0 + 1] = fmaxf(acc[j][1], 0.f);
        sz[r0 + j][c0 + 2] = fmaxf(acc[j][2], 0.f);
        sz[r0 + j][c0 + 3] = fmaxf(acc[j][3], 0.f);
    }
    __syncthreads();
    for (int i = t; i < 64 * NCLS; i += 256) {
        int r = i / NCLS, c = i - r * NCLS;
        int row = row0 + r;
        float s = sb2[c];
        #pragma unroll 8
        for (int k = 0; k < HID; k++) s += sz[r][k] * sW2[k * NCLS + c];
        if (row < n) logits[(size_t)row * NCLS + c] = s;
    }
}

extern "C" void kernel_launch(void* const* d_in, const int* in_sizes, int n_in,
                              void* d_out, int out_size, void* d_ws, size_t ws_size,
                              hipStream_t stream)
{
    const float* x   = (const float*)d_in[0];
    const float* ew  = (const float*)d_in[1];
    const float* Wp  = (const float*)d_in[2];
    const float* Wl  = (const float*)d_in[3];
    const float* bl  = (const float*)d_in[4];
    const float* Wr  = (const float*)d_in[5];
    const float* br  = (const float*)d_in[6];
    const float* att = (const float*)d_in[7];
    const float* We  = (const float*)d_in[8];
    const float* gb  = (const float*)d_in[9];
    const float* W1  = (const float*)d_in[10];
    const float* b1  = (const float*)d_in[11];
    const float* W2  = (const float*)d_in[12];
    const float* b2  = (const float*)d_in[13];
    const int*   ei  = (const int*)d_in[14];

    int n = in_sizes[0] / IN;
    int E = in_sizes[1];
    const int* src = ei;
    const int* dst = ei + E;

    unsigned short* h0h = (unsigned short*)d_ws;          // n*64 bf16
    unsigned short* xlh = h0h + (size_t)n * HID;
    unsigned short* xrh = xlh + (size_t)n * HID;
    int*   cnt   = (int*)(xrh + (size_t)n * HID);         // zeroed
    int*   off   = cnt + n;
    int*   bsum  = off + n;
    int*   boff  = bsum + 1024;
    int*   rank  = boff + 1024;
    int2*  csr   = (int2*)(rank + ((E + 1) & ~1));

    float* hout   = (float*)d_out;
    float* logits = hout + (size_t)n * HID;

    hipMemsetAsync(cnt, 0, (size_t)n * sizeof(int), stream);

    int rb = (n + 63) / 64;
    int nb = (n + 1023) / 1024;
    int Eb4 = (E / 4 + 255) / 256;

    k_hist<<<Eb4, 256, 0, stream>>>(dst, cnt, rank, E);
    k_pre <<<rb, 256, 0, stream>>>(x, Wp, h0h, n);
    k_lr_scan1<<<rb + nb, 256, 0, stream>>>(h0h, Wl, bl, Wr, br, xlh, xrh, n, cnt, off, bsum, rb);
    k_scan2<<<1, 1024, 0, stream>>>(bsum, boff, nb);
    k_scatter<<<Eb4, 256, 0, stream>>>(src, dst, ew, off, boff, rank, csr, E);
    k_agg <<<(n + 3) / 4, 256, 0, stream>>>(off, boff, csr, xlh, xrh, h0h, We, att, gb, hout, n, E);
    k_mlp <<<rb, 256, 0, stream>>>(hout, W1, b1, W2, b2, logits, n);
}

// Round 11
// 337.544 us; speedup vs baseline: 1.2764x; 1.0748x over previous
//
#include <hip/hip_runtime.h>
#include <hip/hip_bf16.h>
#include <math.h>

#define IN   128
#define HID  64
#define HEADS 4
#define NCLS 10

typedef __attribute__((ext_vector_type(8))) short bf16x8;
typedef __attribute__((ext_vector_type(4))) float f32x4;
typedef __attribute__((ext_vector_type(2))) float f32x2;

// f32 -> bf16 bits with round-to-nearest-even
__device__ __forceinline__ unsigned short f2bf(float f) {
    unsigned u = __float_as_uint(f);
    u += 0x7FFFu + ((u >> 16) & 1u);
    return (unsigned short)(u >> 16);
}
__device__ __forceinline__ float bf2f(unsigned short h) {
    return __uint_as_float((unsigned)h << 16);
}
// dword holding bf16 pair (lo=pos 2j, hi=pos 2j+1) -> f32x2
__device__ __forceinline__ f32x2 unpack2(unsigned u) {
    f32x2 r;
    r.x = __uint_as_float(u << 16);
    r.y = __uint_as_float(u & 0xFFFF0000u);
    return r;
}
__device__ __forceinline__ f32x2 max2(f32x2 a, f32x2 b) {
    f32x2 r; r.x = fmaxf(a.x, b.x); r.y = fmaxf(a.y, b.y); return r;
}

template<int CTRL>
__device__ __forceinline__ f32x2 dppadd2(f32x2 x) {
    f32x2 y;
    y.x = __int_as_float(__builtin_amdgcn_update_dpp(0, __float_as_int(x.x), CTRL, 0xF, 0xF, true));
    y.y = __int_as_float(__builtin_amdgcn_update_dpp(0, __float_as_int(x.y), CTRL, 0xF, 0xF, true));
    return x + y;
}
// packed 16-lane-row sum: reduces all 4 heads (2 per row x lo/hi) at once
__device__ __forceinline__ f32x2 sum16_2(f32x2 p) {
    p = dppadd2<0x128>(p);  // row_ror:8
    p = dppadd2<0x124>(p);  // row_ror:4
    p = dppadd2<0x4E>(p);   // quad_perm xor2
    p = dppadd2<0xB1>(p);   // quad_perm xor1
    return p;
}

// ---------------- K0: dst histogram w/ rank capture (8 edges/thread) ----------------
__global__ __launch_bounds__(256) void k_hist(const int* __restrict__ dst, int* __restrict__ cnt,
                                              int* __restrict__ rank, int E)
{
    int e8 = (blockIdx.x * 256 + threadIdx.x) * 8;
    if (e8 + 7 < E) {
        int4 d0 = *(const int4*)&dst[e8];
        int4 d1 = *(const int4*)&dst[e8 + 4];
        int4 r0, r1;
        r0.x = atomicAdd(&cnt[d0.x], 1);
        r0.y = atomicAdd(&cnt[d0.y], 1);
        r0.z = atomicAdd(&cnt[d0.z], 1);
        r0.w = atomicAdd(&cnt[d0.w], 1);
        r1.x = atomicAdd(&cnt[d1.x], 1);
        r1.y = atomicAdd(&cnt[d1.y], 1);
        r1.z = atomicAdd(&cnt[d1.z], 1);
        r1.w = atomicAdd(&cnt[d1.w], 1);
        *(int4*)&rank[e8]     = r0;
        *(int4*)&rank[e8 + 4] = r1;
    } else {
        for (int e = e8; e < E; e++) rank[e] = atomicAdd(&cnt[dst[e]], 1);
    }
}

// ---------------- K1: h0 (bf16) = x @ W_pre via MFMA ----------------
// A[m=lane&15][k=quad*8+j]; B[k=quad*8+j][n=lane&15]; C/D col=lane&15,row=quad*4+reg
__global__ __launch_bounds__(256) void k_pre(const float* __restrict__ x,
                                             const float* __restrict__ Wp,
                                             unsigned short* __restrict__ h0h, int n)
{
    __shared__ unsigned short xb[64][136];   // bf16 x-tile; reused as f32 64x66 scratch
    __shared__ unsigned short wf[8192];      // Wp in MFMA b-fragment order
    int t = threadIdx.x;

    for (int w0 = t * 8; w0 < 8192; w0 += 2048) {
        int c  = w0 >> 11;
        int ks = (w0 >> 9) & 3;
        int lp = (w0 >> 3) & 63;
        int q = lp >> 4, m = lp & 15;
        int nn = c * 16 + m;
        int kb = ks * 32 + q * 8;
        ushort4 a, b;
        a.x = f2bf(Wp[(kb + 0) * HID + nn]);
        a.y = f2bf(Wp[(kb + 1) * HID + nn]);
        a.z = f2bf(Wp[(kb + 2) * HID + nn]);
        a.w = f2bf(Wp[(kb + 3) * HID + nn]);
        b.x = f2bf(Wp[(kb + 4) * HID + nn]);
        b.y = f2bf(Wp[(kb + 5) * HID + nn]);
        b.z = f2bf(Wp[(kb + 6) * HID + nn]);
        b.w = f2bf(Wp[(kb + 7) * HID + nn]);
        *(ushort4*)&wf[w0]     = a;
        *(ushort4*)&wf[w0 + 4] = b;
    }
    int row0 = blockIdx.x * 64;
    for (int i = t; i < 2048; i += 256) {
        int r = i >> 5, c4 = (i & 31) * 4;
        int row = row0 + r;
        float4 v = make_float4(0.f, 0.f, 0.f, 0.f);
        if (row < n) v = *(const float4*)&x[(size_t)row * IN + c4];
        ushort4 hb;
        hb.x = f2bf(v.x); hb.y = f2bf(v.y); hb.z = f2bf(v.z); hb.w = f2bf(v.w);
        *(ushort4*)&xb[r][c4] = hb;
    }
    __syncthreads();

    int wave = t >> 6, lane = t & 63;
    int m = lane & 15, quad = lane >> 4;
    int rbase = wave * 16;

    f32x4 acc0 = {0.f, 0.f, 0.f, 0.f};
    f32x4 acc1 = {0.f, 0.f, 0.f, 0.f};
    f32x4 acc2 = {0.f, 0.f, 0.f, 0.f};
    f32x4 acc3 = {0.f, 0.f, 0.f, 0.f};
    #pragma unroll
    for (int ks = 0; ks < 4; ks++) {
        bf16x8 a = *(const bf16x8*)&xb[rbase + m][ks * 32 + quad * 8];
        bf16x8 b0 = *(const bf16x8*)&wf[((0 * 4 + ks) * 64 + lane) * 8];
        bf16x8 b1 = *(const bf16x8*)&wf[((1 * 4 + ks) * 64 + lane) * 8];
        bf16x8 b2 = *(const bf16x8*)&wf[((2 * 4 + ks) * 64 + lane) * 8];
        bf16x8 b3 = *(const bf16x8*)&wf[((3 * 4 + ks) * 64 + lane) * 8];
        acc0 = __builtin_amdgcn_mfma_f32_16x16x32_bf16(a, b0, acc0, 0, 0, 0);
        acc1 = __builtin_amdgcn_mfma_f32_16x16x32_bf16(a, b1, acc1, 0, 0, 0);
        acc2 = __builtin_amdgcn_mfma_f32_16x16x32_bf16(a, b2, acc2, 0, 0, 0);
        acc3 = __builtin_amdgcn_mfma_f32_16x16x32_bf16(a, b3, acc3, 0, 0, 0);
    }
    __syncthreads();
    float* sc = (float*)&xb[0][0];   // 64 x 66
    #pragma unroll
    for (int r = 0; r < 4; r++) {
        int lrow = rbase + quad * 4 + r;
        sc[lrow * 66 +  0 + m] = acc0[r];
        sc[lrow * 66 + 16 + m] = acc1[r];
        sc[lrow * 66 + 32 + m] = acc2[r];
        sc[lrow * 66 + 48 + m] = acc3[r];
    }
    __syncthreads();
    for (int i = t; i < 1024; i += 256) {
        int r = i >> 4, c4 = (i & 15) * 4;
        int row = row0 + r;
        if (row < n) {
            ushort4 hb;
            hb.x = f2bf(sc[r * 66 + c4 + 0]);
            hb.y = f2bf(sc[r * 66 + c4 + 1]);
            hb.z = f2bf(sc[r * 66 + c4 + 2]);
            hb.w = f2bf(sc[r * 66 + c4 + 3]);
            *(ushort4*)&h0h[(size_t)row * HID + c4] = hb;
        }
    }
}

// ---------------- K2: xl/xr (bf16, PERMUTED pos 2j<-feat j, 2j+1<-feat j+32) via MFMA + scan1 ----------------
__global__ __launch_bounds__(256) void k_lr_scan1(const unsigned short* __restrict__ h0h,
                                                  const float* __restrict__ Wl, const float* __restrict__ bl,
                                                  const float* __restrict__ Wr, const float* __restrict__ br,
                                                  unsigned short* __restrict__ xlh,
                                                  unsigned short* __restrict__ xrh, int n,
                                                  const int* __restrict__ cnt, int* __restrict__ off,
                                                  int* __restrict__ bsum, int rb)
{
    __shared__ unsigned short wfL[4096];
    __shared__ unsigned short wfR[4096];
    __shared__ unsigned short hb[64][72];
    __shared__ float sbl[64], sbr[64];
    int t = threadIdx.x;

    if ((int)blockIdx.x >= rb) {
        int* si = (int*)wfL;
        int bid = (int)blockIdx.x - rb;
        int base = bid * 1024 + t * 4;
        int c0 = 0, c1 = 0, c2 = 0, c3 = 0;
        if (base + 3 < n) {
            int4 c = *(const int4*)&cnt[base];
            c0 = c.x; c1 = c.y; c2 = c.z; c3 = c.w;
        } else {
            if (base     < n) c0 = cnt[base];
            if (base + 1 < n) c1 = cnt[base + 1];
            if (base + 2 < n) c2 = cnt[base + 2];
            if (base + 3 < n) c3 = cnt[base + 3];
        }
        int lsum = c0 + c1 + c2 + c3;
        si[t] = lsum;
        __syncthreads();
        for (int d = 1; d < 256; d <<= 1) {
            int add = (t >= d) ? si[t - d] : 0;
            __syncthreads();
            si[t] += add;
            __syncthreads();
        }
        int excl = si[t] - lsum;
        if (base     < n) off[base]     = excl;
        if (base + 1 < n) off[base + 1] = excl + c0;
        if (base + 2 < n) off[base + 2] = excl + c0 + c1;
        if (base + 3 < n) off[base + 3] = excl + c0 + c1 + c2;
        if (t == 255) bsum[bid] = si[255];
        return;
    }

    for (int w0 = t * 8; w0 < 4096; w0 += 2048) {
        int c  = w0 >> 10;
        int ks = (w0 >> 9) & 1;
        int lp = (w0 >> 3) & 63;
        int q = lp >> 4, m = lp & 15;
        int nn = c * 16 + m;
        int kb = ks * 32 + q * 8;
        ushort4 a, b;
        a.x = f2bf(Wl[(kb + 0) * HID + nn]);
        a.y = f2bf(Wl[(kb + 1) * HID + nn]);
        a.z = f2bf(Wl[(kb + 2) * HID + nn]);
        a.w = f2bf(Wl[(kb + 3) * HID + nn]);
        b.x = f2bf(Wl[(kb + 4) * HID + nn]);
        b.y = f2bf(Wl[(kb + 5) * HID + nn]);
        b.z = f2bf(Wl[(kb + 6) * HID + nn]);
        b.w = f2bf(Wl[(kb + 7) * HID + nn]);
        *(ushort4*)&wfL[w0]     = a;
        *(ushort4*)&wfL[w0 + 4] = b;
        a.x = f2bf(Wr[(kb + 0) * HID + nn]);
        a.y = f2bf(Wr[(kb + 1) * HID + nn]);
        a.z = f2bf(Wr[(kb + 2) * HID + nn]);
        a.w = f2bf(Wr[(kb + 3) * HID + nn]);
        b.x = f2bf(Wr[(kb + 4) * HID + nn]);
        b.y = f2bf(Wr[(kb + 5) * HID + nn]);
        b.z = f2bf(Wr[(kb + 6) * HID + nn]);
        b.w = f2bf(Wr[(kb + 7) * HID + nn]);
        *(ushort4*)&wfR[w0]     = a;
        *(ushort4*)&wfR[w0 + 4] = b;
    }
    if (t < 64) { sbl[t] = bl[t]; sbr[t] = br[t]; }
    int row0 = blockIdx.x * 64;
    for (int i = t; i < 1024; i += 256) {
        int r = i >> 4, c4 = (i & 15) * 4;
        int row = row0 + r;
        ushort4 v = make_ushort4(0, 0, 0, 0);
        if (row < n) v = *(const ushort4*)&h0h[(size_t)row * HID + c4];
        *(ushort4*)&hb[r][c4] = v;
    }
    __syncthreads();

    int wave = t >> 6, lane = t & 63;
    int m = lane & 15, quad = lane >> 4;
    int rbase = wave * 16;

    f32x4 aL0 = {0,0,0,0}, aL1 = {0,0,0,0}, aL2 = {0,0,0,0}, aL3 = {0,0,0,0};
    f32x4 aR0 = {0,0,0,0}, aR1 = {0,0,0,0}, aR2 = {0,0,0,0}, aR3 = {0,0,0,0};
    #pragma unroll
    for (int ks = 0; ks < 2; ks++) {
        bf16x8 a = *(const bf16x8*)&hb[rbase + m][ks * 32 + quad * 8];
        bf16x8 bL0 = *(const bf16x8*)&wfL[((0 * 2 + ks) * 64 + lane) * 8];
        bf16x8 bL1 = *(const bf16x8*)&wfL[((1 * 2 + ks) * 64 + lane) * 8];
        bf16x8 bL2 = *(const bf16x8*)&wfL[((2 * 2 + ks) * 64 + lane) * 8];
        bf16x8 bL3 = *(const bf16x8*)&wfL[((3 * 2 + ks) * 64 + lane) * 8];
        aL0 = __builtin_amdgcn_mfma_f32_16x16x32_bf16(a, bL0, aL0, 0, 0, 0);
        aL1 = __builtin_amdgcn_mfma_f32_16x16x32_bf16(a, bL1, aL1, 0, 0, 0);
        aL2 = __builtin_amdgcn_mfma_f32_16x16x32_bf16(a, bL2, aL2, 0, 0, 0);
        aL3 = __builtin_amdgcn_mfma_f32_16x16x32_bf16(a, bL3, aL3, 0, 0, 0);
        bf16x8 bR0 = *(const bf16x8*)&wfR[((0 * 2 + ks) * 64 + lane) * 8];
        bf16x8 bR1 = *(const bf16x8*)&wfR[((1 * 2 + ks) * 64 + lane) * 8];
        bf16x8 bR2 = *(const bf16x8*)&wfR[((2 * 2 + ks) * 64 + lane) * 8];
        bf16x8 bR3 = *(const bf16x8*)&wfR[((3 * 2 + ks) * 64 + lane) * 8];
        aR0 = __builtin_amdgcn_mfma_f32_16x16x32_bf16(a, bR0, aR0, 0, 0, 0);
        aR1 = __builtin_amdgcn_mfma_f32_16x16x32_bf16(a, bR1, aR1, 0, 0, 0);
        aR2 = __builtin_amdgcn_mfma_f32_16x16x32_bf16(a, bR2, aR2, 0, 0, 0);
        aR3 = __builtin_amdgcn_mfma_f32_16x16x32_bf16(a, bR3, aR3, 0, 0, 0);
    }
    float bL[4] = { sbl[m], sbl[16 + m], sbl[32 + m], sbl[48 + m] };
    float bR[4] = { sbr[m], sbr[16 + m], sbr[32 + m], sbr[48 + m] };
    #pragma unroll
    for (int r = 0; r < 4; r++) {
        aL0[r] += bL[0]; aL1[r] += bL[1]; aL2[r] += bL[2]; aL3[r] += bL[3];
        aR0[r] += bR[0]; aR1[r] += bR[1]; aR2[r] += bR[2]; aR3[r] += bR[3];
    }
    __syncthreads();
    float* sc = (float*)&hb[0][0];   // 32 x 66 f32 scratch

    #pragma unroll
    for (int pass = 0; pass < 4; pass++) {
        int half = pass & 1;
        bool isL = pass < 2;
        if ((wave >> 1) == half) {
            int lrow = (rbase & 31) + quad * 4;
            f32x4 c0 = isL ? aL0 : aR0, c1 = isL ? aL1 : aR1;
            f32x4 c2 = isL ? aL2 : aR2, c3 = isL ? aL3 : aR3;
            #pragma unroll
            for (int r = 0; r < 4; r++) {
                sc[(lrow + r) * 66 +  0 + m] = c0[r];
                sc[(lrow + r) * 66 + 16 + m] = c1[r];
                sc[(lrow + r) * 66 + 32 + m] = c2[r];
                sc[(lrow + r) * 66 + 48 + m] = c3[r];
            }
        }
        __syncthreads();
        unsigned short* dstp = isL ? xlh : xrh;
        for (int i = t; i < 512; i += 256) {
            int r = i >> 4, p4 = (i & 15) * 4;   // p4 = 2j (even)
            int jj = p4 >> 1;
            int row = row0 + half * 32 + r;
            if (row < n) {
                // permuted: pos 2j <- feat j ; pos 2j+1 <- feat j+32
                ushort4 hv;
                hv.x = f2bf(sc[r * 66 + jj]);
                hv.y = f2bf(sc[r * 66 + jj + 32]);
                hv.z = f2bf(sc[r * 66 + jj + 1]);
                hv.w = f2bf(sc[r * 66 + jj + 33]);
                *(ushort4*)&dstp[(size_t)row * HID + p4] = hv;
            }
        }
        __syncthreads();
    }
}

// ---------------- Scan stage 2 ----------------
__global__ __launch_bounds__(1024) void k_scan2(const int* __restrict__ bsum, int* __restrict__ boff, int nb)
{
    __shared__ int s[1024];
    int i = threadIdx.x;
    int v = (i < nb) ? bsum[i] : 0;
    s[i] = v;
    __syncthreads();
    for (int d = 1; d < 1024; d <<= 1) {
        int add = (i >= d) ? s[i - d] : 0;
        __syncthreads();
        s[i] += add;
        __syncthreads();
    }
    if (i < nb) boff[i] = s[i] - v;
}

// ---------------- Scatter into CSR — atomic-free: pos = off[dst] + boff[dst>>10] + rank ----------------
__global__ __launch_bounds__(256) void k_scatter(const int* __restrict__ src, const int* __restrict__ dst,
                                                 const float* __restrict__ ew,
                                                 const int* __restrict__ off, const int* __restrict__ boff,
                                                 const int* __restrict__ rank,
                                                 int2* __restrict__ csr, int E)
{
    int e4 = (blockIdx.x * 256 + threadIdx.x) * 4;
    if (e4 + 3 < E) {
        int4   s4 = *(const int4*)&src[e4];
        int4   d4 = *(const int4*)&dst[e4];
        int4   r4 = *(const int4*)&rank[e4];
        float4 w4 = *(const float4*)&ew[e4];
        int p0 = off[d4.x] + boff[d4.x >> 10] + r4.x;
        int p1 = off[d4.y] + boff[d4.y >> 10] + r4.y;
        int p2 = off[d4.z] + boff[d4.z >> 10] + r4.z;
        int p3 = off[d4.w] + boff[d4.w >> 10] + r4.w;
        csr[p0] = make_int2(s4.x, __float_as_int(w4.x));
        csr[p1] = make_int2(s4.y, __float_as_int(w4.y));
        csr[p2] = make_int2(s4.z, __float_as_int(w4.z));
        csr[p3] = make_int2(s4.w, __float_as_int(w4.w));
    } else {
        for (int e = e4; e < E; e++) {
            int p = off[dst[e]] + boff[dst[e] >> 10] + rank[e];
            csr[p] = make_int2(src[e], __float_as_int(ew[e]));
        }
    }
}

// ---------------- K_agg: 2 edges/wave, 2 packed features/lane; LDS csr broadcast; packed DPP tree ----------------
__global__ __launch_bounds__(256) void k_agg(const int* __restrict__ off, const int* __restrict__ boff,
                                             const int2* __restrict__ csr,
                                             const unsigned short* __restrict__ xlh,
                                             const unsigned short* __restrict__ xrh,
                                             const unsigned short* __restrict__ h0h,
                                             const float* __restrict__ We, const float* __restrict__ att,
                                             const float* __restrict__ gb,
                                             float* __restrict__ hout, int n, int E)
{
    __shared__ float sWe[HID], sAtt[HID], sGb[HID];
    __shared__ int2 sCsr[4][64];
    int t = threadIdx.x;
    if (t < HID) {
        int f = (t >> 1) + 32 * (t & 1);          // permuted layout
        sWe[t] = We[f];
        sAtt[t] = att[f] * 1.44269504f;           // pre-scale by log2(e)
        sGb[t] = gb[f];
    }
    __syncthreads();
    int lane = t & 63;
    int wave = t >> 6;
    int j = lane & 31, h = lane >> 5;
    int v = blockIdx.x * 4 + wave;
    if (v >= n) return;

    int beg = off[v] + boff[v >> 10];
    int end = (v == n - 1) ? E : off[v + 1] + boff[(v + 1) >> 10];

    f32x2 we2, at2;
    we2.x = sWe[2 * j]; we2.y = sWe[2 * j + 1];
    at2.x = sAtt[2 * j]; at2.y = sAtt[2 * j + 1];
    const unsigned* xl32 = (const unsigned*)xlh;
    const unsigned* xr32 = (const unsigned*)xrh;
    f32x2 xr2 = unpack2(xr32[(unsigned)v * 32 + j]);
    f32x2 xl2 = unpack2(xl32[(unsigned)v * 32 + j]);

    f32x2 num = {0.f, 0.f}, den = {0.f, 0.f};
    float wsum = 0.f;
    int2* scw = sCsr[wave];

    for (int base = beg; base < end; base += 64) {
        int m = end - base; if (m > 64) m = 64;
        if (lane < m) scw[lane] = csr[base + lane];     // wave-local; lgkm waits auto
        int mp = m >> 1;
        int p = 0;
        for (; p + 4 <= mp; p += 4) {
            unsigned ug[4]; float wv[4];
            #pragma unroll
            for (int u = 0; u < 4; u++) {
                int2 cw = scw[2 * (p + u) + h];          // per-half edge (src,w)
                wv[u] = __int_as_float(cw.y);
                ug[u] = xl32[(unsigned)cw.x * 32 + j];   // both features in one dword
            }
            #pragma unroll
            for (int u = 0; u < 4; u++) {
                f32x2 xls = unpack2(ug[u]);
                f32x2 ws; ws.x = wv[u]; ws.y = wv[u];
                f32x2 z = xls + xr2 + ws * we2;
                f32x2 ef = max2(z, 0.2f * z);
                f32x2 pk = sum16_2(ef * at2);
                f32x2 ex;
                ex.x = __builtin_amdgcn_exp2f(pk.x);
                ex.y = __builtin_amdgcn_exp2f(pk.y);
                num += ex * xls;
                den += ex;
                wsum += wv[u];
            }
        }
        for (; p < mp; p++) {
            int2 cw = scw[2 * p + h];
            float w = __int_as_float(cw.y);
            f32x2 xls = unpack2(xl32[(unsigned)cw.x * 32 + j]);
            f32x2 ws; ws.x = w; ws.y = w;
            f32x2 z = xls + xr2 + ws * we2;
            f32x2 ef = max2(z, 0.2f * z);
            f32x2 pk = sum16_2(ef * at2);
            f32x2 ex;
            ex.x = __builtin_amdgcn_exp2f(pk.x);
            ex.y = __builtin_amdgcn_exp2f(pk.y);
            num += ex * xls;
            den += ex;
            wsum += w;
        }
        if (m & 1) {
            // odd tail: all lanes compute (halves duplicate), only half 0 accumulates
            int2 cw = scw[m - 1];
            float w = __int_as_float(cw.y);
            f32x2 xls = unpack2(xl32[(unsigned)cw.x * 32 + j]);
            f32x2 ws; ws.x = w; ws.y = w;
            f32x2 z = xls + xr2 + ws * we2;
            f32x2 ef = max2(z, 0.2f * z);
            f32x2 pk = sum16_2(ef * at2);
            f32x2 ex;
            ex.x = __builtin_amdgcn_exp2f(pk.x);
            ex.y = __builtin_amdgcn_exp2f(pk.y);
            if (h == 0) {
                num += ex * xls;
                den += ex;
                wsum += w;
            }
        }
    }
    // merge the two half-wave accumulators
    num.x += __shfl_xor(num.x, 32);
    num.y += __shfl_xor(num.y, 32);
    den.x += __shfl_xor(den.x, 32);
    den.y += __shfl_xor(den.y, 32);
    wsum  += __shfl_xor(wsum, 32);

    // analytic self-loop
    float cntf = (float)(end - beg);
    float la = wsum / fmaxf(cntf, 1.0f);
    f32x2 ls; ls.x = la; ls.y = la;
    f32x2 z = xl2 + xr2 + ls * we2;
    f32x2 ef = max2(z, 0.2f * z);
    f32x2 pk = sum16_2(ef * at2);
    f32x2 ex;
    ex.x = __builtin_amdgcn_exp2f(pk.x);
    ex.y = __builtin_amdgcn_exp2f(pk.y);
    den += ex;
    num += ex * xl2;

    f32x2 gb2; gb2.x = sGb[2 * j]; gb2.y = sGb[2 * j + 1];
    f32x2 o = num / den + gb2;
    float val = (h == 0) ? o.x : o.y;        // lane l holds feature l (lo: j, hi: j+32)
    float h1 = val > 0.f ? val : expm1f(val);
    hout[(size_t)v * HID + lane] = bf2f(h0h[((size_t)v << 6) + lane]) + h1;
}

// ---------------- K_mlp: logits = relu(h@W1+b1)@W2+b2 via MFMA ----------------
__global__ __launch_bounds__(256) void k_mlp(const float* __restrict__ hin,
                                             const float* __restrict__ W1, const float* __restrict__ b1,
                                             const float* __restrict__ W2, const float* __restrict__ b2,
                                             float* __restrict__ logits, int n)
{
    __shared__ unsigned short hb[64][72];   // bf16 h tile
    __shared__ unsigned short zb[64][72];   // bf16 z tile (wave-local rows)
    __shared__ unsigned short wf1[4096];    // W1 frags
    __shared__ unsigned short wf2[1024];    // W2 (64 x 16, cols>=10 zero) frags
    __shared__ float sb1[64], sb2[16];
    int t = threadIdx.x;

    for (int w0 = t * 8; w0 < 4096; w0 += 2048) {
        int c  = w0 >> 10;
        int ks = (w0 >> 9) & 1;
        int lp = (w0 >> 3) & 63;
        int q = lp >> 4, m = lp & 15;
        int nn = c * 16 + m;
        int kb = ks * 32 + q * 8;
        ushort4 a, b;
        a.x = f2bf(W1[(kb + 0) * HID + nn]);
        a.y = f2bf(W1[(kb + 1) * HID + nn]);
        a.z = f2bf(W1[(kb + 2) * HID + nn]);
        a.w = f2bf(W1[(kb + 3) * HID + nn]);
        b.x = f2bf(W1[(kb + 4) * HID + nn]);
        b.y = f2bf(W1[(kb + 5) * HID + nn]);
        b.z = f2bf(W1[(kb + 6) * HID + nn]);
        b.w = f2bf(W1[(kb + 7) * HID + nn]);
        *(ushort4*)&wf1[w0]     = a;
        *(ushort4*)&wf1[w0 + 4] = b;
    }
    for (int i = t; i < 1024; i += 256) {
        int jj = i & 7, lp = (i >> 3) & 63, ks = i >> 9;
        int q = lp >> 4, nn = lp & 15;
        int k = ks * 32 + q * 8 + jj;
        wf2[i] = (nn < NCLS) ? f2bf(W2[k * NCLS + nn]) : (unsigned short)0;
    }
    if (t < 64) sb1[t] = b1[t];
    if (t < 16) sb2[t] = (t < NCLS) ? b2[t] : 0.f;
    int row0 = blockIdx.x * 64;
    for (int i = t; i < 1024; i += 256) {
        int r = i >> 4, c4 = (i & 15) * 4;
        int row = row0 + r;
        float4 v = make_float4(0.f, 0.f, 0.f, 0.f);
        if (row < n) v = *(const float4*)&hin[(size_t)row * HID + c4];
        ushort4 hv;
        hv.x = f2bf(v.x); hv.y = f2bf(v.y); hv.z = f2bf(v.z); hv.w = f2bf(v.w);
        *(ushort4*)&hb[r][c4] = hv;
    }
    __syncthreads();

    int wave = t >> 6, lane = t & 63;
    int m = lane & 15, quad = lane >> 4;
    int rbase = wave * 16;

    f32x4 a0 = {0,0,0,0}, a1 = {0,0,0,0}, a2 = {0,0,0,0}, a3 = {0,0,0,0};
    #pragma unroll
    for (int ks = 0; ks < 2; ks++) {
        bf16x8 a = *(const bf16x8*)&hb[rbase + m][ks * 32 + quad * 8];
        bf16x8 b0 = *(const bf16x8*)&wf1[((0 * 2 + ks) * 64 + lane) * 8];
        bf16x8 b1v = *(const bf16x8*)&wf1[((1 * 2 + ks) * 64 + lane) * 8];
        bf16x8 b2v = *(const bf16x8*)&wf1[((2 * 2 + ks) * 64 + lane) * 8];
        bf16x8 b3v = *(const bf16x8*)&wf1[((3 * 2 + ks) * 64 + lane) * 8];
        a0 = __builtin_amdgcn_mfma_f32_16x16x32_bf16(a, b0, a0, 0, 0, 0);
        a1 = __builtin_amdgcn_mfma_f32_16x16x32_bf16(a, b1v, a1, 0, 0, 0);
        a2 = __builtin_amdgcn_mfma_f32_16x16x32_bf16(a, b2v, a2, 0, 0, 0);
        a3 = __builtin_amdgcn_mfma_f32_16x16x32_bf16(a, b3v, a3, 0, 0, 0);
    }
    // bias + relu, write z (wave-local rows) in bf16
    float bb[4] = { sb1[m], sb1[16 + m], sb1[32 + m], sb1[48 + m] };
    #pragma unroll
    for (int r = 0; r < 4; r++) {
        int zr = rbase + quad * 4 + r;
        zb[zr][ 0 + m] = f2bf(fmaxf(a0[r] + bb[0], 0.f));
        zb[zr][16 + m] = f2bf(fmaxf(a1[r] + bb[1], 0.f));
        zb[zr][32 + m] = f2bf(fmaxf(a2[r] + bb[2], 0.f));
        zb[zr][48 + m] = f2bf(fmaxf(a3[r] + bb[3], 0.f));
    }
    // GEMM2: z (wave's own rows) @ W2pad -> logits ; no barrier needed (wave-local)
    float binit = sb2[m];
    f32x4 acc = { binit, binit, binit, binit };
    #pragma unroll
    for (int ks = 0; ks < 2; ks++) {
        bf16x8 a = *(const bf16x8*)&zb[rbase + m][ks * 32 + quad * 8];
        bf16x8 b = *(const bf16x8*)&wf2[(ks * 64 + lane) * 8];
        acc = __builtin_amdgcn_mfma_f32_16x16x32_bf16(a, b, acc, 0, 0, 0);
    }
    if (m < NCLS) {
        #pragma unroll
        for (int r = 0; r < 4; r++) {
            int row = row0 + rbase + quad * 4 + r;
            if (row < n) logits[(size_t)row * NCLS + m] = acc[r];
        }
    }
}

extern "C" void kernel_launch(void* const* d_in, const int* in_sizes, int n_in,
                              void* d_out, int out_size, void* d_ws, size_t ws_size,
                              hipStream_t stream)
{
    const float* x   = (const float*)d_in[0];
    const float* ew  = (const float*)d_in[1];
    const float* Wp  = (const float*)d_in[2];
    const float* Wl  = (const float*)d_in[3];
    const float* bl  = (const float*)d_in[4];
    const float* Wr  = (const float*)d_in[5];
    const float* br  = (const float*)d_in[6];
    const float* att = (const float*)d_in[7];
    const float* We  = (const float*)d_in[8];
    const float* gb  = (const float*)d_in[9];
    const float* W1  = (const float*)d_in[10];
    const float* b1  = (const float*)d_in[11];
    const float* W2  = (const float*)d_in[12];
    const float* b2  = (const float*)d_in[13];
    const int*   ei  = (const int*)d_in[14];

    int n = in_sizes[0] / IN;
    int E = in_sizes[1];
    const int* src = ei;
    const int* dst = ei + E;

    unsigned short* h0h = (unsigned short*)d_ws;          // n*64 bf16
    unsigned short* xlh = h0h + (size_t)n * HID;          // permuted
    unsigned short* xrh = xlh + (size_t)n * HID;          // permuted
    int*   cnt   = (int*)(xrh + (size_t)n * HID);         // zeroed
    int*   off   = cnt + n;
    int*   bsum  = off + n;
    int*   boff  = bsum + 1024;
    int*   rank  = boff + 1024;
    int2*  csr   = (int2*)(rank + ((E + 1) & ~1));

    float* hout   = (float*)d_out;
    float* logits = hout + (size_t)n * HID;

    hipMemsetAsync(cnt, 0, (size_t)n * sizeof(int), stream);

    int rb = (n + 63) / 64;
    int nb = (n + 1023) / 1024;
    int Eb4 = (E / 4 + 255) / 256;
    int Eb8 = (E / 8 + 255) / 256;

    k_hist<<<Eb8, 256, 0, stream>>>(dst, cnt, rank, E);
    k_pre <<<rb, 256, 0, stream>>>(x, Wp, h0h, n);
    k_lr_scan1<<<rb + nb, 256, 0, stream>>>(h0h, Wl, bl, Wr, br, xlh, xrh, n, cnt, off, bsum, rb);
    k_scan2<<<1, 1024, 0, stream>>>(bsum, boff, nb);
    k_scatter<<<Eb4, 256, 0, stream>>>(src, dst, ew, off, boff, rank, csr, E);
    k_agg <<<(n + 3) / 4, 256, 0, stream>>>(off, boff, csr, xlh, xrh, h0h, We, att, gb, hout, n, E);
    k_mlp <<<rb, 256, 0, stream>>>(hout, W1, b1, W2, b2, logits, n);
}